// Round 1
// baseline (677.449 us; speedup 1.0000x reference)
//
#include <hip/hip_runtime.h>
#include <hip/hip_bf16.h>
#include <math.h>

#define NPOS 16384   // B*H*W = 16*32*32
#define DD   512
#define PP   ((size_t)NPOS * DD)   // 8388608 elements per plane

typedef __bf16 bf16x8 __attribute__((ext_vector_type(8)));
typedef float  f32x4  __attribute__((ext_vector_type(4)));

// ---- async global->LDS, 16B per lane (global_load_lds_dwordx4) ----
__device__ __forceinline__ void gload16(const __bf16* g, __bf16* l) {
  __builtin_amdgcn_global_load_lds((__attribute__((address_space(1))) void*)(g),
                                   (__attribute__((address_space(3))) void*)(l), 16, 0, 0);
}
__device__ __forceinline__ void wait_vm0() { asm volatile("s_waitcnt vmcnt(0)" ::: "memory"); }
__device__ __forceinline__ void wait_vm3() { asm volatile("s_waitcnt vmcnt(3)" ::: "memory"); }
__device__ __forceinline__ void wait_vm4() { asm volatile("s_waitcnt vmcnt(4)" ::: "memory"); }

// ================= bf16 MFMA GEMM, 8-wave counted-vmcnt pipeline =================
// R15: old 2-phase reg-staged 128^2 kernel measured MfmaUtil 13.7 / HBM 15% / VALU 26%
// -> schedule-bound (m233: ~72% of 2-phase K-step is stage+wait+barrier). New structure
// = T2+T3+T4+T5 in plain HIP:
//   * BMxBN = 256x256 (N=1024) or 128x256 (N=512); BK=32; 512 thr = 8 waves (2M x 4N).
//   * 3-deep LDS ring (96/72 KB). Tile t+2 staged during tile t via global_load_lds
//     (16B/lane, lane-linear LDS dest) into the buffer freed at end of tile t-1 -> no
//     overlap with readers; loads in flight ~1.5 K-tiles.
//   * Counted vmcnt: ONE s_waitcnt vmcnt(4|3) per K-tile, placed before the tile-end
//     s_barrier (per-wave wait + barrier => all waves' DMA landed). Never 0 mid-loop.
//   * Global-side XOR swizzle (c ^ ((row>>1)&3)) -> frag ds_read_b128 conflict-free
//     (identical formula to prior kernel; SQ_LDS_BANK_CONFLICT == 0 measured).
//   * s_setprio(1) around each 16-MFMA cluster; raw s_barrier per phase.
// Grid: 1-D, bijective XCD swizzle (nwg=256 % 8 == 0); lin = mt*nbn + ntc with ntc
// fastest -> each XCD owns 32 consecutive lin = contiguous A-panels (A fetched ~1x/XCD).
// epi 0: C0 fp32 (ld N) = acc + bias
// epi 1: N=1024; bn<512 -> C1b bf16 (ld 512); bn>=512 -> sigmoid -> C1 bf16 (ld 512)
// epi 2: C0 fp32 (ld N) = acc + bias + res
template<int BM>
__global__ __launch_bounds__(512, 2) void gemm8p_k(
    const __bf16* __restrict__ A, const __bf16* __restrict__ Bt,
    const float* __restrict__ bias, const float* __restrict__ res,
    float* __restrict__ C0, __bf16* __restrict__ C1, __bf16* __restrict__ C1b,
    int N, int K, int epi)
{
  constexpr int PH = BM / 128;                 // phases (M-halves) per K-tile: 1 or 2
  __shared__ __bf16 Asm[3][BM * 32];
  __shared__ __bf16 Bsm[3][256 * 32];

  const int tid  = threadIdx.x;
  const int w    = tid >> 6;
  const int lane = tid & 63;
  const int quad = lane >> 4;
  const int l16  = lane & 15;
  const int wm   = (w >> 2) * (BM / 2);        // wave M origin (2 M-waves)
  const int wn   = (w & 3) * 64;               // wave N origin (4 N-waves)

  // grid decode: bijective XCD swizzle, then ntc fastest (A-sharers adjacent per XCD)
  const int nwg = gridDim.x;
  const int cpx = nwg >> 3;
  const int lin = (blockIdx.x & 7) * cpx + (blockIdx.x >> 3);
  const int nbn = N >> 8;                      // 256-wide N tiles (2 or 4)
  const int sh  = (nbn == 4) ? 2 : 1;
  const int mt  = lin >> sh;
  const int ntc = lin & (nbn - 1);
  const int bm  = mt * BM;
  const int bn  = ntc << 8;

  const __bf16* Ab = A  + (size_t)bm * K;
  const __bf16* Bb = Bt + (size_t)bn * K;
  const int nk = K >> 5;

  f32x4 acc[4 * PH][4];
  #pragma unroll
  for (int i = 0; i < 4 * PH; ++i)
    #pragma unroll
    for (int j = 0; j < 4; ++j) acc[i][j] = (f32x4){0.f, 0.f, 0.f, 0.f};

  // staging: chunk id ch -> LDS byte off ch*16 (lane-linear per wave, gload_lds-legal);
  // global col-chunk pre-swizzled so swizzled frag reads see linear data (rule 21).
  #define STG_A(tile, buf, k2) {                                               \
    const int ch_ = tid + (k2) * 512;                                          \
    const int r_ = ch_ >> 2, c_ = ch_ & 3;                                     \
    gload16(Ab + (size_t)r_ * K + ((tile) << 5) + ((c_ ^ ((r_ >> 1) & 3)) << 3),\
            &Asm[buf][ch_ << 3]);                                              \
  }
  #define STG_B(tile, buf, k2) {                                               \
    const int ch_ = tid + (k2) * 512;                                          \
    const int r_ = ch_ >> 2, c_ = ch_ & 3;                                     \
    gload16(Bb + (size_t)r_ * K + ((tile) << 5) + ((c_ ^ ((r_ >> 1) & 3)) << 3),\
            &Bsm[buf][ch_ << 3]);                                              \
  }

  // prologue: stage tiles 0,1; wait tile 0 (allow tile 1 in flight); barrier
  STG_A(0, 0, 0)
  if constexpr (BM == 256) STG_A(0, 0, 1)
  STG_B(0, 0, 0)
  STG_B(0, 0, 1)
  STG_A(1, 1, 0)
  if constexpr (BM == 256) STG_A(1, 1, 1)
  STG_B(1, 1, 0)
  STG_B(1, 1, 1)
  if constexpr (BM == 256) { wait_vm4(); } else { wait_vm3(); }
  __builtin_amdgcn_s_barrier();

  int cur = 0;
  for (int t = 0; t < nk; ++t) {
    const int nx2 = (cur == 0) ? 2 : cur - 1;    // (cur+2)%3 : buffer for tile t+2
    const bool st = (t + 2 < nk);
    bf16x8 af[4], bfr[4];

    // ---- phase 0: frags (A half0 + all B) | stage | bar | MFMA x16 | [bar] ----
    #pragma unroll
    for (int i = 0; i < 4; ++i) {
      const int m = wm + i * 16 + l16;
      af[i] = *(const bf16x8*)(&Asm[cur][m * 32 + ((quad ^ ((m >> 1) & 3)) << 3)]);
    }
    #pragma unroll
    for (int j = 0; j < 4; ++j) {
      const int n = wn + j * 16 + l16;
      bfr[j] = *(const bf16x8*)(&Bsm[cur][n * 32 + ((quad ^ ((n >> 1) & 3)) << 3)]);
    }
    if (st) {
      STG_A(t + 2, nx2, 0)
      STG_B(t + 2, nx2, 0)
      if constexpr (BM == 128) STG_B(t + 2, nx2, 1)
    }
    __builtin_amdgcn_s_barrier();
    __builtin_amdgcn_s_setprio(1);
    #pragma unroll
    for (int i = 0; i < 4; ++i)
      #pragma unroll
      for (int j = 0; j < 4; ++j)
        acc[i][j] = __builtin_amdgcn_mfma_f32_16x16x32_bf16(af[i], bfr[j], acc[i][j], 0, 0, 0);
    __builtin_amdgcn_s_setprio(0);

    if constexpr (BM == 256) {
      // ---- phase 1: frags (A half1; B reused) | stage | bar | MFMA x16 ----
      __builtin_amdgcn_s_barrier();
      #pragma unroll
      for (int i = 0; i < 4; ++i) {
        const int m = wm + 64 + i * 16 + l16;
        af[i] = *(const bf16x8*)(&Asm[cur][m * 32 + ((quad ^ ((m >> 1) & 3)) << 3)]);
      }
      if (st) {
        STG_A(t + 2, nx2, 1)
        STG_B(t + 2, nx2, 1)
      }
      __builtin_amdgcn_s_barrier();
      __builtin_amdgcn_s_setprio(1);
      #pragma unroll
      for (int i = 0; i < 4; ++i)
        #pragma unroll
        for (int j = 0; j < 4; ++j)
          acc[4 + i][j] = __builtin_amdgcn_mfma_f32_16x16x32_bf16(af[i], bfr[j], acc[4 + i][j], 0, 0, 0);
      __builtin_amdgcn_s_setprio(0);
    }

    // ---- tile end: counted wait (tile t+1 landed; tile t+2's loads stay in flight) ----
    if (st) { if constexpr (BM == 256) { wait_vm4(); } else { wait_vm3(); } }
    else    { wait_vm0(); }
    __builtin_amdgcn_s_barrier();
    cur = (cur == 2) ? 0 : cur + 1;
  }
  #undef STG_A
  #undef STG_B

  // epilogue. C/D layout: col = lane&15, row = quad*4 + reg  [m89-verified]
  const bool dosig = (epi == 1) && (bn >= 512);
  #pragma unroll
  for (int j = 0; j < 4; ++j) {
    const int col = wn + j * 16 + l16;
    const float bv = bias[bn + col];
    #pragma unroll
    for (int i = 0; i < 4 * PH; ++i) {
      const int row0 = bm + wm + (i >> 2) * 64 + (i & 3) * 16 + quad * 4;
      #pragma unroll
      for (int r = 0; r < 4; ++r) {
        float v = acc[i][j][r] + bv;
        if (epi == 1) {
          if (dosig) {
            v = 1.f / (1.f + expf(-v));
            C1[(size_t)(row0 + r) * 512 + (bn - 512) + col] = (__bf16)v;
          } else {
            C1b[(size_t)(row0 + r) * 512 + bn + col] = (__bf16)v;
          }
        } else {
          size_t off = (size_t)(row0 + r) * N + bn + col;
          if (epi == 2) v += res[off];
          C0[off] = v;
        }
      }
    }
  }
}

// ---------------- fp32 -> bf16 elementwise (tokens) ----------------
__global__ __launch_bounds__(256) void cvt_k(const float* __restrict__ s, __bf16* __restrict__ d)
{
  size_t i = ((size_t)blockIdx.x * 256 + threadIdx.x) * 8;
  float4 a = *(const float4*)(s + i);
  float4 b = *(const float4*)(s + i + 4);
  bf16x8 v;
  v[0] = (__bf16)a.x; v[1] = (__bf16)a.y; v[2] = (__bf16)a.z; v[3] = (__bf16)a.w;
  v[4] = (__bf16)b.x; v[5] = (__bf16)b.y; v[6] = (__bf16)b.z; v[7] = (__bf16)b.w;
  *(bf16x8*)(d + i) = v;
}

// ---------------- transpose KxN fp32 -> NxK bf16 (weights) ----------------
__global__ __launch_bounds__(256) void tr_k(const float* __restrict__ src, __bf16* __restrict__ dst,
                                            int K, int N, size_t sstr, size_t dstr)
{
  __shared__ float t[32][33];
  const float* s = src + blockIdx.z * sstr;
  __bf16* d = dst + blockIdx.z * dstr;
  int n0 = blockIdx.x * 32, k0 = blockIdx.y * 32;
  int tx = threadIdx.x & 31, ty = threadIdx.x >> 5;   // 32x8
  #pragma unroll
  for (int i = 0; i < 4; ++i)
    t[ty + i * 8][tx] = s[(size_t)(k0 + ty + i * 8) * N + n0 + tx];
  __syncthreads();
  #pragma unroll
  for (int i = 0; i < 4; ++i)
    d[(size_t)(n0 + ty + i * 8) * K + k0 + tx] = (__bf16)t[tx][ty + i * 8];
}

// ---------------- LayerNorm over D=512, one wave per position, bf16 out ----------------
__global__ __launch_bounds__(256) void ln_k(const float* __restrict__ x, const float* __restrict__ w,
                                            const float* __restrict__ bv, __bf16* __restrict__ out)
{
  int gw = (blockIdx.x * 256 + threadIdx.x) >> 6;   // position
  int lane = threadIdx.x & 63;
  const float* xp = x + ((size_t)gw << 9) + lane * 8;
  float4 u0 = *(const float4*)xp;
  float4 u1 = *(const float4*)(xp + 4);
  float v[8] = {u0.x,u0.y,u0.z,u0.w,u1.x,u1.y,u1.z,u1.w};
  float s = 0.f;
  #pragma unroll
  for (int j = 0; j < 8; ++j) s += v[j];
  #pragma unroll
  for (int off = 32; off; off >>= 1) s += __shfl_xor(s, off, 64);
  float mu = s * (1.f/512.f);
  float q = 0.f;
  #pragma unroll
  for (int j = 0; j < 8; ++j) { float d = v[j] - mu; q += d*d; }
  #pragma unroll
  for (int off = 32; off; off >>= 1) q += __shfl_xor(q, off, 64);
  float rstd = rsqrtf(q * (1.f/512.f) + 1e-5f);
  int dch = lane * 8;
  float4 w0 = *(const float4*)(w + dch),  w1 = *(const float4*)(w + dch + 4);
  float4 b0 = *(const float4*)(bv + dch), b1 = *(const float4*)(bv + dch + 4);
  float wv[8] = {w0.x,w0.y,w0.z,w0.w,w1.x,w1.y,w1.z,w1.w};
  float bb[8] = {b0.x,b0.y,b0.z,b0.w,b1.x,b1.y,b1.z,b1.w};
  bf16x8 ov;
  #pragma unroll
  for (int j = 0; j < 8; ++j) ov[j] = (__bf16)((v[j] - mu) * rstd * wv[j] + bb[j]);
  *(bf16x8*)(out + ((size_t)gw << 9) + dch) = ov;
}

// ================= Fully-fused conv + 2D scan, chunk-interleaved (R13/R14-proven) =================
__device__ __forceinline__ float sig_a(float al) {
  float a = 1.f / (1.f + expf(-al));
  return fminf(fmaxf(a, 1e-4f), 1.f - 1e-4f);
}

__global__ __launch_bounds__(512, 2) void scan2d_k(
    const __bf16* __restrict__ xin, const float* __restrict__ cw, const float* __restrict__ cb,
    const float* __restrict__ alog, const float* __restrict__ bvec, const float* __restrict__ cvec,
    const float* __restrict__ dvec, const __bf16* __restrict__ gate, __bf16* __restrict__ yo)
{
  __shared__ __bf16 T[32768];       // xin tile [pos][32 ch]; partial park in phase C. 64 KB
  __shared__ __bf16 Y[32768];       // u tile. 64 KB
  __shared__ float  S[4][32][32];   // chunk sums: rowF,rowB,colF,colB. 16 KB
  const int tid = threadIdx.x;
  const int cg  = blockIdx.x;       // channel group of 32
  const int b   = blockIdx.y;
  const int ch  = tid & 31;
  const int c0  = tid >> 5;         // 0..15; thread owns chunks c0 and c0+16
  const int c1  = c0 + 16;
  const int d   = (cg << 5) + ch;

  const float a   = sig_a(alog[d]);
  const float lna = logf(a);
  const float ia  = 1.f / a;
  const float bb  = bvec[d];
  const float sc  = 0.25f * cvec[d];
  const float dd  = dvec[d];

  const __bf16* ub = xin + ((size_t)b << 19) + (cg << 5);

  // ---- load xin tile: 8 x bf16x8 per thread, 16 B/lane coalesced ----
  #pragma unroll
  for (int i = 0; i < 8; ++i) {
    int flat = (tid + i * 512) << 3;
    int pos = flat >> 5;
    int c8  = flat & 31;
    *(bf16x8*)(T + flat) = *(const bf16x8*)(ub + (size_t)pos * 512 + c8);
  }
  // conv weights while loads are in flight
  float w00 = cw[(0 << 9) + d], w01 = cw[(1 << 9) + d], w02 = cw[(2 << 9) + d];
  float w10 = cw[(3 << 9) + d], w11 = cw[(4 << 9) + d], w12 = cw[(5 << 9) + d];
  float w20 = cw[(6 << 9) + d], w21 = cw[(7 << 9) + d], w22 = cw[(8 << 9) + d];
  const float cbv = cb[d];
  // scan bases (loop-invariant; direct expf avoids 0*inf at extreme a)
  const float A0f = expf((float)(c0 << 5) * lna),        R0f = expf((float)(c0 << 5) * -lna);
  const float A1f = expf((float)(c1 << 5) * lna),        R1f = expf((float)(c1 << 5) * -lna);
  const float A0b = expf((float)((31 - c0) << 5) * lna), R0b = expf((float)((31 - c0) << 5) * -lna);
  const float A1b = expf((float)((31 - c1) << 5) * lna), R1b = expf((float)((31 - c1) << 5) * -lna);
  __syncthreads();

  // ---- phase 0: depthwise 3x3 conv + SiLU, rows c0 & c1 interleaved -> Y ----
  {
    const bool up0 = (c0 > 0);      // row c0-1 valid (c0+1 always <= 16 valid)
    const bool dn1 = (c0 < 15);     // row c1+1 valid (c1-1 always >= 15 valid)
    float a0 = 0.f, a1 = 0.f, a2 = 0.f, f0 = 0.f, f1 = 0.f, f2 = 0.f;   // col -1
    float b0 = up0 ? (float)T[(((c0 - 1) << 5)) * 32 + ch] : 0.f;        // col 0
    float b1 =        (float)T[((c0 << 5)) * 32 + ch];
    float b2 =        (float)T[(((c0 + 1) << 5)) * 32 + ch];
    float g0 =        (float)T[(((c1 - 1) << 5)) * 32 + ch];
    float g1 =        (float)T[((c1 << 5)) * 32 + ch];
    float g2 = dn1 ? (float)T[(((c1 + 1) << 5)) * 32 + ch] : 0.f;
    #pragma unroll 4
    for (int ww = 0; ww < 32; ++ww) {
      float e0 = 0.f, e1 = 0.f, e2 = 0.f, i0 = 0.f, i1 = 0.f, i2 = 0.f;  // col ww+1
      if (ww < 31) {
        e0 = up0 ? (float)T[(((c0 - 1) << 5) + ww + 1) * 32 + ch] : 0.f;
        e1 =        (float)T[((c0 << 5) + ww + 1) * 32 + ch];
        e2 =        (float)T[(((c0 + 1) << 5) + ww + 1) * 32 + ch];
        i0 =        (float)T[(((c1 - 1) << 5) + ww + 1) * 32 + ch];
        i1 =        (float)T[((c1 << 5) + ww + 1) * 32 + ch];
        i2 = dn1 ? (float)T[(((c1 + 1) << 5) + ww + 1) * 32 + ch] : 0.f;
      }
      float acc0 = cbv, acc1 = cbv;
      acc0 = fmaf(a0, w00, acc0); acc0 = fmaf(b0, w01, acc0); acc0 = fmaf(e0, w02, acc0);
      acc0 = fmaf(a1, w10, acc0); acc0 = fmaf(b1, w11, acc0); acc0 = fmaf(e1, w12, acc0);
      acc0 = fmaf(a2, w20, acc0); acc0 = fmaf(b2, w21, acc0); acc0 = fmaf(e2, w22, acc0);
      acc1 = fmaf(f0, w00, acc1); acc1 = fmaf(g0, w01, acc1); acc1 = fmaf(i0, w02, acc1);
      acc1 = fmaf(f1, w10, acc1); acc1 = fmaf(g1, w11, acc1); acc1 = fmaf(i1, w12, acc1);
      acc1 = fmaf(f2, w20, acc1); acc1 = fmaf(g2, w21, acc1); acc1 = fmaf(i2, w22, acc1);
      acc0 = acc0 / (1.f + expf(-acc0));
      acc1 = acc1 / (1.f + expf(-acc1));
      Y[((c0 << 5) + ww) * 32 + ch] = (__bf16)acc0;
      Y[((c1 << 5) + ww) * 32 + ch] = (__bf16)acc1;
      a0 = b0; a1 = b1; a2 = b2; b0 = e0; b1 = e1; b2 = e2;
      f0 = g0; f1 = g1; f2 = g2; g0 = i0; g1 = i1; g2 = i2;
    }
  }
  __syncthreads();

  // one scan step: r += u*bb/max(apr,1e-20) with tracked reciprocal
  #define STEP(r_, uu_, apr_, rp_)                                 \
    { float rr_ = (apr_ < 1e-20f) ? 1e20f : rp_;                   \
      r_ = fmaf((uu_) * bb, rr_, r_); }

  // ---- phase A: 8 chunk sums (2 chunks x rowF/rowB/colF/colB) in one loop ----
  {
    float p0 = A0f, q0 = R0f, p0B = A0b, q0B = R0b;
    float p1 = A1f, q1 = R1f, p1B = A1b, q1B = R1b;
    float s0 = 0.f, s1 = 0.f, s2 = 0.f, s3 = 0.f;
    float s4 = 0.f, s5 = 0.f, s6 = 0.f, s7 = 0.f;
    #pragma unroll 4
    for (int j = 0; j < 32; ++j) {
      float u0rf = (float)Y[((c0 << 5) + j) * 32 + ch];
      float u0rb = (float)Y[((c0 << 5) + (31 - j)) * 32 + ch];
      float u0cf = (float)Y[((j << 5) | c0) * 32 + ch];
      float u0cb = (float)Y[(((31 - j) << 5) | c0) * 32 + ch];
      float u1rf = (float)Y[((c1 << 5) + j) * 32 + ch];
      float u1rb = (float)Y[((c1 << 5) + (31 - j)) * 32 + ch];
      float u1cf = (float)Y[((j << 5) | c1) * 32 + ch];
      float u1cb = (float)Y[(((31 - j) << 5) | c1) * 32 + ch];
      STEP(s0, u0rf, p0, q0)  STEP(s2, u0cf, p0, q0)
      STEP(s1, u0rb, p0B, q0B) STEP(s3, u0cb, p0B, q0B)
      STEP(s4, u1rf, p1, q1)  STEP(s6, u1cf, p1, q1)
      STEP(s5, u1rb, p1B, q1B) STEP(s7, u1cb, p1B, q1B)
      p0 *= a; q0 *= ia; p0B *= a; q0B *= ia;
      p1 *= a; q1 *= ia; p1B *= a; q1B *= ia;
    }
    S[0][c0][ch] = s0; S[1][c0][ch] = s1; S[2][c0][ch] = s2; S[3][c0][ch] = s3;
    S[0][c1][ch] = s4; S[1][c1][ch] = s5; S[2][c1][ch] = s6; S[3][c1][ch] = s7;
  }
  __syncthreads();

  // ---- phase B: exclusive prefix (F arrays) / exclusive suffix (B arrays) ----
  if (tid < 128) {
    int arr = tid >> 5, ch2 = tid & 31;
    float run = 0.f;
    if ((arr & 1) == 0) {
      #pragma unroll 4
      for (int cc = 0; cc < 32; ++cc) { float v = S[arr][cc][ch2]; S[arr][cc][ch2] = run; run += v; }
    } else {
      #pragma unroll 4
      for (int cc = 31; cc >= 0; --cc) { float v = S[arr][cc][ch2]; S[arr][cc][ch2] = run; run += v; }
    }
  }
  __syncthreads();

  // ---- C-col fwd (both chunks): raw partial -> T ----
  {
    float r0 = S[2][c0][ch], r1 = S[2][c1][ch];
    float p0 = A0f, q0 = R0f, p1 = A1f, q1 = R1f;
    #pragma unroll 4
    for (int j = 0; j < 32; ++j) {
      int i0 = ((j << 5) | c0) * 32 + ch, i1 = ((j << 5) | c1) * 32 + ch;
      float u0 = (float)Y[i0], u1 = (float)Y[i1];
      float ap0 = fmaxf(p0, 1e-20f), ap1 = fmaxf(p1, 1e-20f);
      STEP(r0, u0, p0, q0) STEP(r1, u1, p1, q1)
      T[i0] = (__bf16)(r0 * ap0);
      T[i1] = (__bf16)(r1 * ap1);
      p0 *= a; q0 *= ia; p1 *= a; q1 *= ia;
    }
  }
  // ---- C-col bwd (both chunks): T = sc*(T + r*ap)  [same-thread RMW] ----
  {
    float r0 = S[3][c0][ch], r1 = S[3][c1][ch];
    float p0 = A0b, q0 = R0b, p1 = A1b, q1 = R1b;
    #pragma unroll 4
    for (int j = 31; j >= 0; --j) {
      int i0 = ((j << 5) | c0) * 32 + ch, i1 = ((j << 5) | c1) * 32 + ch;
      float u0 = (float)Y[i0], u1 = (float)Y[i1];
      float ap0 = fmaxf(p0, 1e-20f), ap1 = fmaxf(p1, 1e-20f);
      STEP(r0, u0, p0, q0) STEP(r1, u1, p1, q1)
      T[i0] = (__bf16)(sc * ((float)T[i0] + r0 * ap0));
      T[i1] = (__bf16)(sc * ((float)T[i1] + r1 * ap1));
      p0 *= a; q0 *= ia; p1 *= a; q1 *= ia;
    }
  }
  __syncthreads();   // row threads read other threads' col finals

  // ---- C-row fwd (both chunks): T += sc*(r*ap) ----
  {
    float r0 = S[0][c0][ch], r1 = S[0][c1][ch];
    float p0 = A0f, q0 = R0f, p1 = A1f, q1 = R1f;
    #pragma unroll 4
    for (int j = 0; j < 32; ++j) {
      int i0 = ((c0 << 5) + j) * 32 + ch, i1 = ((c1 << 5) + j) * 32 + ch;
      float u0 = (float)Y[i0], u1 = (float)Y[i1];
      float ap0 = fmaxf(p0, 1e-20f), ap1 = fmaxf(p1, 1e-20f);
      STEP(r0, u0, p0, q0) STEP(r1, u1, p1, q1)
      T[i0] = (__bf16)((float)T[i0] + sc * (r0 * ap0));
      T[i1] = (__bf16)((float)T[i1] + sc * (r1 * ap1));
      p0 *= a; q0 *= ia; p1 *= a; q1 *= ia;
    }
  }
  // ---- C-row bwd (both chunks): finalize + d*u, *gate, write out ----
  {
    const __bf16* gb = gate + ((size_t)b << 19) + (cg << 5) + ch;
    __bf16* yb = yo + ((size_t)b << 19) + (cg << 5) + ch;
    float r0 = S[1][c0][ch], r1 = S[1][c1][ch];
    float p0 = A0b, q0 = R0b, p1 = A1b, q1 = R1b;
    #pragma unroll 4
    for (int j = 31; j >= 0; --j) {
      int pp0 = (c0 << 5) + j, pp1 = (c1 << 5) + j;
      int i0 = pp0 * 32 + ch, i1 = pp1 * 32 + ch;
      float u0 = (float)Y[i0], u1 = (float)Y[i1];
      float ap0 = fmaxf(p0, 1e-20f), ap1 = fmaxf(p1, 1e-20f);
      STEP(r0, u0, p0, q0) STEP(r1, u1, p1, q1)
      float y0 = (float)T[i0] + sc * (r0 * ap0) + dd * u0;
      float y1 = (float)T[i1] + sc * (r1 * ap1) + dd * u1;
      yb[(size_t)pp0 * 512] = (__bf16)(y0 * (float)gb[(size_t)pp0 * 512]);
      yb[(size_t)pp1 * 512] = (__bf16)(y1 * (float)gb[(size_t)pp1 * 512]);
      p0 *= a; q0 *= ia; p1 *= a; q1 *= ia;
    }
  }
  #undef STEP
}

// ---------------- mean over 1024 positions (bf16 in) -> (16, 512) fp32 ----------------
__global__ __launch_bounds__(256) void reduce_k(const __bf16* __restrict__ hn, float* __restrict__ out)
{
  __shared__ float part[4][64];
  int l = threadIdx.x & 63;       // channel within group
  int q = threadIdx.x >> 6;       // position quarter
  int d = blockIdx.y * 64 + l;
  int b = blockIdx.x;
  const __bf16* p = hn + ((size_t)b << 19) + d + ((size_t)(q * 256) << 9);
  float s0 = 0.f, s1 = 0.f, s2 = 0.f, s3 = 0.f;
  for (int t = 0; t < 256; t += 4) {
    s0 += (float)p[(size_t)(t+0) << 9];
    s1 += (float)p[(size_t)(t+1) << 9];
    s2 += (float)p[(size_t)(t+2) << 9];
    s3 += (float)p[(size_t)(t+3) << 9];
  }
  part[q][l] = (s0 + s1) + (s2 + s3);
  __syncthreads();
  if (threadIdx.x < 64)
    out[b * 512 + d] = (part[0][l] + part[1][l] + part[2][l] + part[3][l]) * (1.f / 1024.f);
}

extern "C" void kernel_launch(void* const* d_in, const int* in_sizes, int n_in,
                              void* d_out, int out_size, void* d_ws, size_t ws_size,
                              hipStream_t stream)
{
  const float* tokens = (const float*)d_in[0];
  const float* in_w   = (const float*)d_in[1];
  const float* in_b   = (const float*)d_in[2];
  const float* nw     = (const float*)d_in[3];
  const float* nb     = (const float*)d_in[4];
  const float* iw     = (const float*)d_in[5];
  const float* ib     = (const float*)d_in[6];
  const float* cw     = (const float*)d_in[7];
  const float* cb     = (const float*)d_in[8];
  const float* al     = (const float*)d_in[9];
  const float* bbv    = (const float*)d_in[10];
  const float* ccv    = (const float*)d_in[11];
  const float* ddv    = (const float*)d_in[12];
  const float* ow     = (const float*)d_in[13];
  const float* obv    = (const float*)d_in[14];
  const float* onw    = (const float*)d_in[15];
  const float* onb    = (const float*)d_in[16];

  // workspace layout (~115 MB):
  float*  x     = (float*)d_ws;                      // fp32 residual (33.5 MB)
  __bf16* hy16  = (__bf16*)(x + PP);                 // bf16 h / yg / final-ln (16.8 MB)
  __bf16* xin16 = hy16 + PP;                         // bf16 x_in (16.8 MB)
  __bf16* g16   = xin16 + PP;                        // bf16 gate (16.8 MB)
  __bf16* iwT   = g16 + PP;                          // 4x(1024x512) bf16 (4.2 MB)
  __bf16* owT   = iwT + (size_t)4 * 1024 * 512;      // 4x(512x512) bf16 (2.1 MB)
  __bf16* tb16  = owT + (size_t)4 * 512 * 512;       // tokens bf16 (25.2 MB)
  __bf16* inwT  = xin16;                             // in_proj_w^T bf16 (pre-loop alias)

  // --- weight/input conversion (once per launch) ---
  cvt_k<<<6144, 256, 0, stream>>>(tokens, tb16);
  tr_k<<<dim3(16, 24, 1), 256, 0, stream>>>(in_w, inwT, 768, 512, 0, 0);
  tr_k<<<dim3(32, 16, 4), 256, 0, stream>>>(iw, iwT, 512, 1024, (size_t)512*1024, (size_t)1024*512);
  tr_k<<<dim3(16, 16, 4), 256, 0, stream>>>(ow, owT, 512, 512, (size_t)512*512, (size_t)512*512);

  // x = tokens @ in_proj_w + b   (BM=128: 128 M-tiles x 2 N-tiles = 256 blocks)
  gemm8p_k<128><<<256, 512, 0, stream>>>(tb16, inwT, in_b, nullptr, x, nullptr, nullptr,
                                         512, 768, 0);

  for (int i = 0; i < 4; ++i) {
    ln_k<<<4096, 256, 0, stream>>>(x, nw + i*512, nb + i*512, hy16);
    // (h @ iw + ib): BM=256: 64 x 4 = 256 blocks
    gemm8p_k<256><<<256, 512, 0, stream>>>(hy16, iwT + (size_t)i*1024*512, ib + i*1024,
                                           nullptr, nullptr, g16, xin16, 1024, 512, 1);
    scan2d_k<<<dim3(16, 16), 512, 0, stream>>>(xin16, cw + i*9*512, cb + i*512,
                                               al + i*512, bbv + i*512, ccv + i*512,
                                               ddv + i*512, g16, hy16);
    // (yg @ ow + ob + x): BM=128: 128 x 2 = 256 blocks
    gemm8p_k<128><<<256, 512, 0, stream>>>(hy16, owT + (size_t)i*512*512, obv + i*512,
                                           x, x, nullptr, nullptr, 512, 512, 2);
  }

  ln_k<<<4096, 256, 0, stream>>>(x, onw, onb, hy16);
  reduce_k<<<dim3(16, 8), 256, 0, stream>>>(hy16, (float*)d_out);
}

// Round 3
// 641.110 us; speedup vs baseline: 1.0567x; 1.0567x over previous
//
#include <hip/hip_runtime.h>
#include <hip/hip_bf16.h>
#include <math.h>

#define NPOS 16384   // B*H*W = 16*32*32
#define DD   512
#define PP   ((size_t)NPOS * DD)   // 8388608 elements per plane

typedef __bf16 bf16x8 __attribute__((ext_vector_type(8)));
typedef float  f32x4  __attribute__((ext_vector_type(4)));

// ---- async global->LDS, 16B per lane (global_load_lds_dwordx4) ----
__device__ __forceinline__ void gload16(const __bf16* g, __bf16* l) {
  __builtin_amdgcn_global_load_lds((__attribute__((address_space(1))) void*)(g),
                                   (__attribute__((address_space(3))) void*)(l), 16, 0, 0);
}
__device__ __forceinline__ void wait_vm0() { asm volatile("s_waitcnt vmcnt(0)" ::: "memory"); }
__device__ __forceinline__ void wait_vm4() { asm volatile("s_waitcnt vmcnt(4)" ::: "memory"); }
__device__ __forceinline__ void wait_lgkm0() { asm volatile("s_waitcnt lgkmcnt(0)" ::: "memory"); }

// ================= bf16 MFMA GEMM, 128x128 / 4 waves / 3-deep gload_lds ring =================
// R16 post-mortem of R15: 256^2 1-block/CU epilogue burst caused half-line (32B) bf16
// stores to double-writeback (WRITE_SIZE 42->79MB); K-loop speed unchanged. This round:
//   * 128x128 tile, 256 thr (4 waves, 2Mx2N), 48KB LDS -> 3 blocks/CU: cross-block
//     overlap (what made the R14 kernel work) PLUS:
//   * global_load_lds 16B staging (m151: 874 vs 646 TF vs reg-staging at this tile),
//     3-deep ring: tile t+2 staged during tile t; counted s_waitcnt vmcnt(4) at tile
//     end (t+1 landed, t+2's 4 loads stay in flight). ONE barrier per K-tile.
//   * Global-side XOR swizzle (c ^ ((row>>1)&3)): frag ds_read_b128 conflict-free
//     (formula carried from R14/R15; SQ_LDS_BANK_CONFLICT == 0 measured).
//   * epi1 (bf16 out): full-line epilogue via per-wave LDS shuffle ([64][72] bf16,
//     row stride 144B = 9x16B) -> bf16x8 stores, 16B/lane, full 64B lines.
//     epi0/2 (fp32 out): direct stores already cover full lines (16 lanes x 4B).
// Grid: 1-D, bijective XCD swizzle (nwg % 8 == 0); ntc fastest -> A-sharers same XCD.
// epi 0: C0 fp32 (ld N) = acc + bias
// epi 1: N=1024; bn<512 -> C1b bf16 (ld 512); bn>=512 -> sigmoid -> C1 bf16 (ld 512)
// epi 2: C0 fp32 (ld N) = acc + bias + res
__global__ __launch_bounds__(256, 3) void gemm_k(
    const __bf16* __restrict__ A, const __bf16* __restrict__ Bt,
    const float* __restrict__ bias, const float* __restrict__ res,
    float* __restrict__ C0, __bf16* __restrict__ C1, __bf16* __restrict__ C1b,
    int N, int K, int epi)
{
  __shared__ __bf16 Asm[3][128 * 32];   // 24 KB
  __shared__ __bf16 Bsm[3][128 * 32];   // 24 KB

  const int tid  = threadIdx.x;
  const int w    = tid >> 6;
  const int lane = tid & 63;
  const int quad = lane >> 4;
  const int l16  = lane & 15;
  const int wm   = (w >> 1) << 6;       // 2 M-waves
  const int wn   = (w & 1) << 6;        // 2 N-waves

  // grid decode: bijective XCD swizzle, then ntc fastest (A-sharers adjacent per XCD)
  const int nwg = gridDim.x;
  const int cpx = nwg >> 3;
  const int lin = (blockIdx.x & 7) * cpx + (blockIdx.x >> 3);
  const int nbn = N >> 7;               // 128-wide N tiles (4 or 8)
  const int sh  = (nbn == 8) ? 3 : 2;
  const int mt  = lin >> sh;
  const int ntc = lin & (nbn - 1);
  const int bm  = mt << 7;
  const int bn  = ntc << 7;

  const __bf16* Ab = A  + (size_t)bm * K;
  const __bf16* Bb = Bt + (size_t)bn * K;
  const int nk = K >> 5;

  f32x4 acc[4][4];
  #pragma unroll
  for (int i = 0; i < 4; ++i)
    #pragma unroll
    for (int j = 0; j < 4; ++j) acc[i][j] = (f32x4){0.f, 0.f, 0.f, 0.f};

  // staging: 512 chunks of 8 elems per 128x32 tile; 2 issues per plane per tile.
  // LDS is lane-linear (gload_lds requirement); global col-chunk pre-swizzled so the
  // swizzled frag reads see linear data (rule 21): LDS[r][sl] = G[r][sl ^ ((r>>1)&3)].
  #define STG(P, gb, tile, buf, k2) {                                           \
    const int ch_ = tid + ((k2) << 8);                                          \
    const int r_ = ch_ >> 2, c_ = ch_ & 3;                                      \
    gload16(gb + (size_t)r_ * K + ((tile) << 5) + ((c_ ^ ((r_ >> 1) & 3)) << 3),\
            &P[buf][ch_ << 3]);                                                 \
  }

  // prologue: stage tiles 0,1 (8 loads); wait first 4 (tile 0... interleaved A/B per
  // tile: issue order = A0,A0,B0,B0,A1,A1,B1,B1 -> vmcnt(4) leaves tile1's 4 in flight)
  STG(Asm, Ab, 0, 0, 0) STG(Asm, Ab, 0, 0, 1)
  STG(Bsm, Bb, 0, 0, 0) STG(Bsm, Bb, 0, 0, 1)
  STG(Asm, Ab, 1, 1, 0) STG(Asm, Ab, 1, 1, 1)
  STG(Bsm, Bb, 1, 1, 0) STG(Bsm, Bb, 1, 1, 1)
  wait_vm4();
  __builtin_amdgcn_s_barrier();

  int cur = 0;
  for (int t = 0; t < nk; ++t) {
    const int nx2 = (cur == 0) ? 2 : cur - 1;    // (cur+2)%3 : buffer for tile t+2
    const bool st = (t + 2 < nk);

    // issue next-next tile's loads FIRST (max latency cover; target buffer was fully
    // read in tile t-1, barrier-ordered before these stores)
    if (st) {
      STG(Asm, Ab, t + 2, nx2, 0) STG(Asm, Ab, t + 2, nx2, 1)
      STG(Bsm, Bb, t + 2, nx2, 0) STG(Bsm, Bb, t + 2, nx2, 1)
    }

    // frag reads from buf[cur] (landed: tile-(t-1)-end waited vmcnt(4))
    bf16x8 af[4], bfr[4];
    #pragma unroll
    for (int i = 0; i < 4; ++i) {
      const int m = wm + i * 16 + l16;
      af[i] = *(const bf16x8*)(&Asm[cur][m * 32 + ((quad ^ ((m >> 1) & 3)) << 3)]);
    }
    #pragma unroll
    for (int j = 0; j < 4; ++j) {
      const int n = wn + j * 16 + l16;
      bfr[j] = *(const bf16x8*)(&Bsm[cur][n * 32 + ((quad ^ ((n >> 1) & 3)) << 3)]);
    }

    __builtin_amdgcn_s_setprio(1);
    #pragma unroll
    for (int i = 0; i < 4; ++i)
      #pragma unroll
      for (int j = 0; j < 4; ++j)
        acc[i][j] = __builtin_amdgcn_mfma_f32_16x16x32_bf16(af[i], bfr[j], acc[i][j], 0, 0, 0);
    __builtin_amdgcn_s_setprio(0);

    // tile end: counted wait (tile t+1 landed; tile t+2's 4 loads stay in flight)
    if (st) { wait_vm4(); } else { wait_vm0(); }
    __builtin_amdgcn_s_barrier();
    cur = (cur == 2) ? 0 : cur + 1;
  }
  #undef STG

  // ---- epilogue. C/D layout: col = lane&15, row = quad*4 + reg  [m89-verified] ----
  if (epi == 1) {
    // full-line bf16 path: scatter through per-wave LDS [64][72] bf16 (stride 144B),
    // read back bf16x8 -> 16B/lane stores; each wave-store covers full 64B lines.
    const bool dosig = (bn >= 512);
    __bf16* dst = dosig ? C1 : C1b;
    const int cb = dosig ? (bn - 512) : bn;
    char* wb = (char*)Asm + w * 9216;            // 4 waves x 9216 B <= 24 KB (ring free)
    #pragma unroll
    for (int i = 0; i < 4; ++i)
      #pragma unroll
      for (int j = 0; j < 4; ++j) {
        const float bv = bias[bn + wn + j * 16 + l16];
        #pragma unroll
        for (int r = 0; r < 4; ++r) {
          float v = acc[i][j][r] + bv;
          if (dosig) v = 1.f / (1.f + expf(-v));
          *(__bf16*)(wb + (i * 16 + quad * 4 + r) * 144 + (j * 16 + l16) * 2) = (__bf16)v;
        }
      }
    wait_lgkm0();                                 // wave-local; no barrier needed
    #pragma unroll
    for (int i = 0; i < 4; ++i)
      #pragma unroll
      for (int h = 0; h < 2; ++h) {
        const int rr = (lane >> 3) + h * 8;       // 0..15 within i-block
        bf16x8 vv = *(bf16x8*)(wb + (i * 16 + rr) * 144 + (lane & 7) * 16);
        const int grow = bm + wm + i * 16 + rr;
        *(bf16x8*)(dst + (size_t)grow * 512 + cb + wn + (lane & 7) * 8) = vv;
      }
  } else {
    // fp32 path: 16 lanes x 4B = full 64B line per store group already
    #pragma unroll
    for (int j = 0; j < 4; ++j) {
      const int col = wn + j * 16 + l16;
      const float bv = bias[bn + col];
      #pragma unroll
      for (int i = 0; i < 4; ++i) {
        const int row0 = bm + wm + i * 16 + quad * 4;
        #pragma unroll
        for (int r = 0; r < 4; ++r) {
          float v = acc[i][j][r] + bv;
          size_t off = (size_t)(row0 + r) * N + bn + col;
          if (epi == 2) v += res[off];
          C0[off] = v;
        }
      }
    }
  }
}

// ---------------- fp32 -> bf16 elementwise (tokens) ----------------
__global__ __launch_bounds__(256) void cvt_k(const float* __restrict__ s, __bf16* __restrict__ d)
{
  size_t i = ((size_t)blockIdx.x * 256 + threadIdx.x) * 8;
  float4 a = *(const float4*)(s + i);
  float4 b = *(const float4*)(s + i + 4);
  bf16x8 v;
  v[0] = (__bf16)a.x; v[1] = (__bf16)a.y; v[2] = (__bf16)a.z; v[3] = (__bf16)a.w;
  v[4] = (__bf16)b.x; v[5] = (__bf16)b.y; v[6] = (__bf16)b.z; v[7] = (__bf16)b.w;
  *(bf16x8*)(d + i) = v;
}

// ---------------- transpose KxN fp32 -> NxK bf16 (weights) ----------------
__global__ __launch_bounds__(256) void tr_k(const float* __restrict__ src, __bf16* __restrict__ dst,
                                            int K, int N, size_t sstr, size_t dstr)
{
  __shared__ float t[32][33];
  const float* s = src + blockIdx.z * sstr;
  __bf16* d = dst + blockIdx.z * dstr;
  int n0 = blockIdx.x * 32, k0 = blockIdx.y * 32;
  int tx = threadIdx.x & 31, ty = threadIdx.x >> 5;   // 32x8
  #pragma unroll
  for (int i = 0; i < 4; ++i)
    t[ty + i * 8][tx] = s[(size_t)(k0 + ty + i * 8) * N + n0 + tx];
  __syncthreads();
  #pragma unroll
  for (int i = 0; i < 4; ++i)
    d[(size_t)(n0 + ty + i * 8) * K + k0 + tx] = (__bf16)t[tx][ty + i * 8];
}

// ---------------- LayerNorm over D=512, one wave per position, bf16 out ----------------
__global__ __launch_bounds__(256) void ln_k(const float* __restrict__ x, const float* __restrict__ w,
                                            const float* __restrict__ bv, __bf16* __restrict__ out)
{
  int gw = (blockIdx.x * 256 + threadIdx.x) >> 6;   // position
  int lane = threadIdx.x & 63;
  const float* xp = x + ((size_t)gw << 9) + lane * 8;
  float4 u0 = *(const float4*)xp;
  float4 u1 = *(const float4*)(xp + 4);
  float v[8] = {u0.x,u0.y,u0.z,u0.w,u1.x,u1.y,u1.z,u1.w};
  float s = 0.f;
  #pragma unroll
  for (int j = 0; j < 8; ++j) s += v[j];
  #pragma unroll
  for (int off = 32; off; off >>= 1) s += __shfl_xor(s, off, 64);
  float mu = s * (1.f/512.f);
  float q = 0.f;
  #pragma unroll
  for (int j = 0; j < 8; ++j) { float d = v[j] - mu; q += d*d; }
  #pragma unroll
  for (int off = 32; off; off >>= 1) q += __shfl_xor(q, off, 64);
  float rstd = rsqrtf(q * (1.f/512.f) + 1e-5f);
  int dch = lane * 8;
  float4 w0 = *(const float4*)(w + dch),  w1 = *(const float4*)(w + dch + 4);
  float4 b0 = *(const float4*)(bv + dch), b1 = *(const float4*)(bv + dch + 4);
  float wv[8] = {w0.x,w0.y,w0.z,w0.w,w1.x,w1.y,w1.z,w1.w};
  float bb[8] = {b0.x,b0.y,b0.z,b0.w,b1.x,b1.y,b1.z,b1.w};
  bf16x8 ov;
  #pragma unroll
  for (int j = 0; j < 8; ++j) ov[j] = (__bf16)((v[j] - mu) * rstd * wv[j] + bb[j]);
  *(bf16x8*)(out + ((size_t)gw << 9) + dch) = ov;
}

// ================= Fully-fused conv + 2D scan, chunk-interleaved (R13/R14-proven) =================
__device__ __forceinline__ float sig_a(float al) {
  float a = 1.f / (1.f + expf(-al));
  return fminf(fmaxf(a, 1e-4f), 1.f - 1e-4f);
}

__global__ __launch_bounds__(512, 2) void scan2d_k(
    const __bf16* __restrict__ xin, const float* __restrict__ cw, const float* __restrict__ cb,
    const float* __restrict__ alog, const float* __restrict__ bvec, const float* __restrict__ cvec,
    const float* __restrict__ dvec, const __bf16* __restrict__ gate, __bf16* __restrict__ yo)
{
  __shared__ __bf16 T[32768];       // xin tile [pos][32 ch]; partial park in phase C. 64 KB
  __shared__ __bf16 Y[32768];       // u tile. 64 KB
  __shared__ float  S[4][32][32];   // chunk sums: rowF,rowB,colF,colB. 16 KB
  const int tid = threadIdx.x;
  const int cg  = blockIdx.x;       // channel group of 32
  const int b   = blockIdx.y;
  const int ch  = tid & 31;
  const int c0  = tid >> 5;         // 0..15; thread owns chunks c0 and c0+16
  const int c1  = c0 + 16;
  const int d   = (cg << 5) + ch;

  const float a   = sig_a(alog[d]);
  const float lna = logf(a);
  const float ia  = 1.f / a;
  const float bb  = bvec[d];
  const float sc  = 0.25f * cvec[d];
  const float dd  = dvec[d];

  const __bf16* ub = xin + ((size_t)b << 19) + (cg << 5);

  // ---- load xin tile: 8 x bf16x8 per thread, 16 B/lane coalesced ----
  #pragma unroll
  for (int i = 0; i < 8; ++i) {
    int flat = (tid + i * 512) << 3;
    int pos = flat >> 5;
    int c8  = flat & 31;
    *(bf16x8*)(T + flat) = *(const bf16x8*)(ub + (size_t)pos * 512 + c8);
  }
  // conv weights while loads are in flight
  float w00 = cw[(0 << 9) + d], w01 = cw[(1 << 9) + d], w02 = cw[(2 << 9) + d];
  float w10 = cw[(3 << 9) + d], w11 = cw[(4 << 9) + d], w12 = cw[(5 << 9) + d];
  float w20 = cw[(6 << 9) + d], w21 = cw[(7 << 9) + d], w22 = cw[(8 << 9) + d];
  const float cbv = cb[d];
  // scan bases (loop-invariant; direct expf avoids 0*inf at extreme a)
  const float A0f = expf((float)(c0 << 5) * lna),        R0f = expf((float)(c0 << 5) * -lna);
  const float A1f = expf((float)(c1 << 5) * lna),        R1f = expf((float)(c1 << 5) * -lna);
  const float A0b = expf((float)((31 - c0) << 5) * lna), R0b = expf((float)((31 - c0) << 5) * -lna);
  const float A1b = expf((float)((31 - c1) << 5) * lna), R1b = expf((float)((31 - c1) << 5) * -lna);
  __syncthreads();

  // ---- phase 0: depthwise 3x3 conv + SiLU, rows c0 & c1 interleaved -> Y ----
  {
    const bool up0 = (c0 > 0);      // row c0-1 valid (c0+1 always <= 16 valid)
    const bool dn1 = (c0 < 15);     // row c1+1 valid (c1-1 always >= 15 valid)
    float a0 = 0.f, a1 = 0.f, a2 = 0.f, f0 = 0.f, f1 = 0.f, f2 = 0.f;   // col -1
    float b0 = up0 ? (float)T[(((c0 - 1) << 5)) * 32 + ch] : 0.f;        // col 0
    float b1 =        (float)T[((c0 << 5)) * 32 + ch];
    float b2 =        (float)T[(((c0 + 1) << 5)) * 32 + ch];
    float g0 =        (float)T[(((c1 - 1) << 5)) * 32 + ch];
    float g1 =        (float)T[((c1 << 5)) * 32 + ch];
    float g2 = dn1 ? (float)T[(((c1 + 1) << 5)) * 32 + ch] : 0.f;
    #pragma unroll 4
    for (int ww = 0; ww < 32; ++ww) {
      float e0 = 0.f, e1 = 0.f, e2 = 0.f, i0 = 0.f, i1 = 0.f, i2 = 0.f;  // col ww+1
      if (ww < 31) {
        e0 = up0 ? (float)T[(((c0 - 1) << 5) + ww + 1) * 32 + ch] : 0.f;
        e1 =        (float)T[((c0 << 5) + ww + 1) * 32 + ch];
        e2 =        (float)T[(((c0 + 1) << 5) + ww + 1) * 32 + ch];
        i0 =        (float)T[(((c1 - 1) << 5) + ww + 1) * 32 + ch];
        i1 =        (float)T[((c1 << 5) + ww + 1) * 32 + ch];
        i2 = dn1 ? (float)T[(((c1 + 1) << 5) + ww + 1) * 32 + ch] : 0.f;
      }
      float acc0 = cbv, acc1 = cbv;
      acc0 = fmaf(a0, w00, acc0); acc0 = fmaf(b0, w01, acc0); acc0 = fmaf(e0, w02, acc0);
      acc0 = fmaf(a1, w10, acc0); acc0 = fmaf(b1, w11, acc0); acc0 = fmaf(e1, w12, acc0);
      acc0 = fmaf(a2, w20, acc0); acc0 = fmaf(b2, w21, acc0); acc0 = fmaf(e2, w22, acc0);
      acc1 = fmaf(f0, w00, acc1); acc1 = fmaf(g0, w01, acc1); acc1 = fmaf(i0, w02, acc1);
      acc1 = fmaf(f1, w10, acc1); acc1 = fmaf(g1, w11, acc1); acc1 = fmaf(i1, w12, acc1);
      acc1 = fmaf(f2, w20, acc1); acc1 = fmaf(g2, w21, acc1); acc1 = fmaf(i2, w22, acc1);
      acc0 = acc0 / (1.f + expf(-acc0));
      acc1 = acc1 / (1.f + expf(-acc1));
      Y[((c0 << 5) + ww) * 32 + ch] = (__bf16)acc0;
      Y[((c1 << 5) + ww) * 32 + ch] = (__bf16)acc1;
      a0 = b0; a1 = b1; a2 = b2; b0 = e0; b1 = e1; b2 = e2;
      f0 = g0; f1 = g1; f2 = g2; g0 = i0; g1 = i1; g2 = i2;
    }
  }
  __syncthreads();

  // one scan step: r += u*bb/max(apr,1e-20) with tracked reciprocal
  #define STEP(r_, uu_, apr_, rp_)                                 \
    { float rr_ = (apr_ < 1e-20f) ? 1e20f : rp_;                   \
      r_ = fmaf((uu_) * bb, rr_, r_); }

  // ---- phase A: 8 chunk sums (2 chunks x rowF/rowB/colF/colB) in one loop ----
  {
    float p0 = A0f, q0 = R0f, p0B = A0b, q0B = R0b;
    float p1 = A1f, q1 = R1f, p1B = A1b, q1B = R1b;
    float s0 = 0.f, s1 = 0.f, s2 = 0.f, s3 = 0.f;
    float s4 = 0.f, s5 = 0.f, s6 = 0.f, s7 = 0.f;
    #pragma unroll 4
    for (int j = 0; j < 32; ++j) {
      float u0rf = (float)Y[((c0 << 5) + j) * 32 + ch];
      float u0rb = (float)Y[((c0 << 5) + (31 - j)) * 32 + ch];
      float u0cf = (float)Y[((j << 5) | c0) * 32 + ch];
      float u0cb = (float)Y[(((31 - j) << 5) | c0) * 32 + ch];
      float u1rf = (float)Y[((c1 << 5) + j) * 32 + ch];
      float u1rb = (float)Y[((c1 << 5) + (31 - j)) * 32 + ch];
      float u1cf = (float)Y[((j << 5) | c1) * 32 + ch];
      float u1cb = (float)Y[(((31 - j) << 5) | c1) * 32 + ch];
      STEP(s0, u0rf, p0, q0)  STEP(s2, u0cf, p0, q0)
      STEP(s1, u0rb, p0B, q0B) STEP(s3, u0cb, p0B, q0B)
      STEP(s4, u1rf, p1, q1)  STEP(s6, u1cf, p1, q1)
      STEP(s5, u1rb, p1B, q1B) STEP(s7, u1cb, p1B, q1B)
      p0 *= a; q0 *= ia; p0B *= a; q0B *= ia;
      p1 *= a; q1 *= ia; p1B *= a; q1B *= ia;
    }
    S[0][c0][ch] = s0; S[1][c0][ch] = s1; S[2][c0][ch] = s2; S[3][c0][ch] = s3;
    S[0][c1][ch] = s4; S[1][c1][ch] = s5; S[2][c1][ch] = s6; S[3][c1][ch] = s7;
  }
  __syncthreads();

  // ---- phase B: exclusive prefix (F arrays) / exclusive suffix (B arrays) ----
  if (tid < 128) {
    int arr = tid >> 5, ch2 = tid & 31;
    float run = 0.f;
    if ((arr & 1) == 0) {
      #pragma unroll 4
      for (int cc = 0; cc < 32; ++cc) { float v = S[arr][cc][ch2]; S[arr][cc][ch2] = run; run += v; }
    } else {
      #pragma unroll 4
      for (int cc = 31; cc >= 0; --cc) { float v = S[arr][cc][ch2]; S[arr][cc][ch2] = run; run += v; }
    }
  }
  __syncthreads();

  // ---- C-col fwd (both chunks): raw partial -> T ----
  {
    float r0 = S[2][c0][ch], r1 = S[2][c1][ch];
    float p0 = A0f, q0 = R0f, p1 = A1f, q1 = R1f;
    #pragma unroll 4
    for (int j = 0; j < 32; ++j) {
      int i0 = ((j << 5) | c0) * 32 + ch, i1 = ((j << 5) | c1) * 32 + ch;
      float u0 = (float)Y[i0], u1 = (float)Y[i1];
      float ap0 = fmaxf(p0, 1e-20f), ap1 = fmaxf(p1, 1e-20f);
      STEP(r0, u0, p0, q0) STEP(r1, u1, p1, q1)
      T[i0] = (__bf16)(r0 * ap0);
      T[i1] = (__bf16)(r1 * ap1);
      p0 *= a; q0 *= ia; p1 *= a; q1 *= ia;
    }
  }
  // ---- C-col bwd (both chunks): T = sc*(T + r*ap)  [same-thread RMW] ----
  {
    float r0 = S[3][c0][ch], r1 = S[3][c1][ch];
    float p0 = A0b, q0 = R0b, p1 = A1b, q1 = R1b;
    #pragma unroll 4
    for (int j = 31; j >= 0; --j) {
      int i0 = ((j << 5) | c0) * 32 + ch, i1 = ((j << 5) | c1) * 32 + ch;
      float u0 = (float)Y[i0], u1 = (float)Y[i1];
      float ap0 = fmaxf(p0, 1e-20f), ap1 = fmaxf(p1, 1e-20f);
      STEP(r0, u0, p0, q0) STEP(r1, u1, p1, q1)
      T[i0] = (__bf16)(sc * ((float)T[i0] + r0 * ap0));
      T[i1] = (__bf16)(sc * ((float)T[i1] + r1 * ap1));
      p0 *= a; q0 *= ia; p1 *= a; q1 *= ia;
    }
  }
  __syncthreads();   // row threads read other threads' col finals

  // ---- C-row fwd (both chunks): T += sc*(r*ap) ----
  {
    float r0 = S[0][c0][ch], r1 = S[0][c1][ch];
    float p0 = A0f, q0 = R0f, p1 = A1f, q1 = R1f;
    #pragma unroll 4
    for (int j = 0; j < 32; ++j) {
      int i0 = ((c0 << 5) + j) * 32 + ch, i1 = ((c1 << 5) + j) * 32 + ch;
      float u0 = (float)Y[i0], u1 = (float)Y[i1];
      float ap0 = fmaxf(p0, 1e-20f), ap1 = fmaxf(p1, 1e-20f);
      STEP(r0, u0, p0, q0) STEP(r1, u1, p1, q1)
      T[i0] = (__bf16)((float)T[i0] + sc * (r0 * ap0));
      T[i1] = (__bf16)((float)T[i1] + sc * (r1 * ap1));
      p0 *= a; q0 *= ia; p1 *= a; q1 *= ia;
    }
  }
  // ---- C-row bwd (both chunks): finalize + d*u, *gate, write out ----
  {
    const __bf16* gb = gate + ((size_t)b << 19) + (cg << 5) + ch;
    __bf16* yb = yo + ((size_t)b << 19) + (cg << 5) + ch;
    float r0 = S[1][c0][ch], r1 = S[1][c1][ch];
    float p0 = A0b, q0 = R0b, p1 = A1b, q1 = R1b;
    #pragma unroll 4
    for (int j = 31; j >= 0; --j) {
      int pp0 = (c0 << 5) + j, pp1 = (c1 << 5) + j;
      int i0 = pp0 * 32 + ch, i1 = pp1 * 32 + ch;
      float u0 = (float)Y[i0], u1 = (float)Y[i1];
      float ap0 = fmaxf(p0, 1e-20f), ap1 = fmaxf(p1, 1e-20f);
      STEP(r0, u0, p0, q0) STEP(r1, u1, p1, q1)
      float y0 = (float)T[i0] + sc * (r0 * ap0) + dd * u0;
      float y1 = (float)T[i1] + sc * (r1 * ap1) + dd * u1;
      yb[(size_t)pp0 * 512] = (__bf16)(y0 * (float)gb[(size_t)pp0 * 512]);
      yb[(size_t)pp1 * 512] = (__bf16)(y1 * (float)gb[(size_t)pp1 * 512]);
      p0 *= a; q0 *= ia; p1 *= a; q1 *= ia;
    }
  }
  #undef STEP
}

// ---------------- mean over 1024 positions (bf16 in) -> (16, 512) fp32 ----------------
__global__ __launch_bounds__(256) void reduce_k(const __bf16* __restrict__ hn, float* __restrict__ out)
{
  __shared__ float part[4][64];
  int l = threadIdx.x & 63;       // channel within group
  int q = threadIdx.x >> 6;       // position quarter
  int d = blockIdx.y * 64 + l;
  int b = blockIdx.x;
  const __bf16* p = hn + ((size_t)b << 19) + d + ((size_t)(q * 256) << 9);
  float s0 = 0.f, s1 = 0.f, s2 = 0.f, s3 = 0.f;
  for (int t = 0; t < 256; t += 4) {
    s0 += (float)p[(size_t)(t+0) << 9];
    s1 += (float)p[(size_t)(t+1) << 9];
    s2 += (float)p[(size_t)(t+2) << 9];
    s3 += (float)p[(size_t)(t+3) << 9];
  }
  part[q][l] = (s0 + s1) + (s2 + s3);
  __syncthreads();
  if (threadIdx.x < 64)
    out[b * 512 + d] = (part[0][l] + part[1][l] + part[2][l] + part[3][l]) * (1.f / 1024.f);
}

extern "C" void kernel_launch(void* const* d_in, const int* in_sizes, int n_in,
                              void* d_out, int out_size, void* d_ws, size_t ws_size,
                              hipStream_t stream)
{
  const float* tokens = (const float*)d_in[0];
  const float* in_w   = (const float*)d_in[1];
  const float* in_b   = (const float*)d_in[2];
  const float* nw     = (const float*)d_in[3];
  const float* nb     = (const float*)d_in[4];
  const float* iw     = (const float*)d_in[5];
  const float* ib     = (const float*)d_in[6];
  const float* cw     = (const float*)d_in[7];
  const float* cb     = (const float*)d_in[8];
  const float* al     = (const float*)d_in[9];
  const float* bbv    = (const float*)d_in[10];
  const float* ccv    = (const float*)d_in[11];
  const float* ddv    = (const float*)d_in[12];
  const float* ow     = (const float*)d_in[13];
  const float* obv    = (const float*)d_in[14];
  const float* onw    = (const float*)d_in[15];
  const float* onb    = (const float*)d_in[16];

  // workspace layout (~115 MB):
  float*  x     = (float*)d_ws;                      // fp32 residual (33.5 MB)
  __bf16* hy16  = (__bf16*)(x + PP);                 // bf16 h / yg / final-ln (16.8 MB)
  __bf16* xin16 = hy16 + PP;                         // bf16 x_in (16.8 MB)
  __bf16* g16   = xin16 + PP;                        // bf16 gate (16.8 MB)
  __bf16* iwT   = g16 + PP;                          // 4x(1024x512) bf16 (4.2 MB)
  __bf16* owT   = iwT + (size_t)4 * 1024 * 512;      // 4x(512x512) bf16 (2.1 MB)
  __bf16* tb16  = owT + (size_t)4 * 512 * 512;       // tokens bf16 (25.2 MB)
  __bf16* inwT  = xin16;                             // in_proj_w^T bf16 (pre-loop alias)

  // --- weight/input conversion (once per launch) ---
  cvt_k<<<6144, 256, 0, stream>>>(tokens, tb16);
  tr_k<<<dim3(16, 24, 1), 256, 0, stream>>>(in_w, inwT, 768, 512, 0, 0);
  tr_k<<<dim3(32, 16, 4), 256, 0, stream>>>(iw, iwT, 512, 1024, (size_t)512*1024, (size_t)1024*512);
  tr_k<<<dim3(16, 16, 4), 256, 0, stream>>>(ow, owT, 512, 512, (size_t)512*512, (size_t)512*512);

  // x = tokens @ in_proj_w + b   (128 M-tiles x 4 N-tiles = 512 blocks, 2/CU)
  gemm_k<<<512, 256, 0, stream>>>(tb16, inwT, in_b, nullptr, x, nullptr, nullptr,
                                  512, 768, 0);

  for (int i = 0; i < 4; ++i) {
    ln_k<<<4096, 256, 0, stream>>>(x, nw + i*512, nb + i*512, hy16);
    // (h @ iw + ib): 128 x 8 = 1024 blocks, 3/CU resident
    gemm_k<<<1024, 256, 0, stream>>>(hy16, iwT + (size_t)i*1024*512, ib + i*1024,
                                     nullptr, nullptr, g16, xin16, 1024, 512, 1);
    scan2d_k<<<dim3(16, 16), 512, 0, stream>>>(xin16, cw + i*9*512, cb + i*512,
                                               al + i*512, bbv + i*512, ccv + i*512,
                                               ddv + i*512, g16, hy16);
    // (yg @ ow + ob + x): 128 x 4 = 512 blocks
    gemm_k<<<512, 256, 0, stream>>>(hy16, owT + (size_t)i*512*512, obv + i*512,
                                    x, x, nullptr, nullptr, 512, 512, 2);
  }

  ln_k<<<4096, 256, 0, stream>>>(x, onw, onb, hy16);
  reduce_k<<<dim3(16, 8), 256, 0, stream>>>(hy16, (float*)d_out);
}

// Round 4
// 604.977 us; speedup vs baseline: 1.1198x; 1.0597x over previous
//
#include <hip/hip_runtime.h>
#include <hip/hip_bf16.h>
#include <math.h>

#define NPOS 16384   // B*H*W = 16*32*32
#define DD   512
#define PP   ((size_t)NPOS * DD)   // 8388608 elements per plane

typedef __bf16 bf16x8 __attribute__((ext_vector_type(8)));
typedef float  f32x4  __attribute__((ext_vector_type(4)));

// ---- async global->LDS, 16B per lane (global_load_lds_dwordx4) ----
__device__ __forceinline__ void gload16(const __bf16* g, __bf16* l) {
  __builtin_amdgcn_global_load_lds((__attribute__((address_space(1))) void*)(g),
                                   (__attribute__((address_space(3))) void*)(l), 16, 0, 0);
}
__device__ __forceinline__ void wait_vm0() { asm volatile("s_waitcnt vmcnt(0)" ::: "memory"); }
__device__ __forceinline__ void wait_vm4() { asm volatile("s_waitcnt vmcnt(4)" ::: "memory"); }
__device__ __forceinline__ void wait_lgkm0() { asm volatile("s_waitcnt lgkmcnt(0)" ::: "memory"); }

// ================= bf16 MFMA GEMM, 128x128 / 4 waves / 3-deep gload_lds ring =================
// R3-verified (GEMMs dropped out of top-5): 128x128 tile, 3 blocks/CU, global_load_lds
// 16B staging into a 3-deep ring, counted s_waitcnt vmcnt(4) (never 0 mid-loop), one
// barrier per K-tile, global-side XOR swizzle for conflict-free frag reads, full-line
// bf16 epilogue via per-wave LDS shuffle (epi1).
// epi 0: C0 fp32 (ld N) = acc + bias
// epi 1: N=1024; bn<512 -> C1b bf16 (ld 512); bn>=512 -> sigmoid -> C1 bf16 (ld 512)
// epi 2: C0 fp32 (ld N) = acc + bias + res
__global__ __launch_bounds__(256, 3) void gemm_k(
    const __bf16* __restrict__ A, const __bf16* __restrict__ Bt,
    const float* __restrict__ bias, const float* __restrict__ res,
    float* __restrict__ C0, __bf16* __restrict__ C1, __bf16* __restrict__ C1b,
    int N, int K, int epi)
{
  __shared__ __bf16 Asm[3][128 * 32];   // 24 KB
  __shared__ __bf16 Bsm[3][128 * 32];   // 24 KB

  const int tid  = threadIdx.x;
  const int w    = tid >> 6;
  const int lane = tid & 63;
  const int quad = lane >> 4;
  const int l16  = lane & 15;
  const int wm   = (w >> 1) << 6;       // 2 M-waves
  const int wn   = (w & 1) << 6;        // 2 N-waves

  // grid decode: bijective XCD swizzle, then ntc fastest (A-sharers adjacent per XCD)
  const int nwg = gridDim.x;
  const int cpx = nwg >> 3;
  const int lin = (blockIdx.x & 7) * cpx + (blockIdx.x >> 3);
  const int nbn = N >> 7;               // 128-wide N tiles (4 or 8)
  const int sh  = (nbn == 8) ? 3 : 2;
  const int mt  = lin >> sh;
  const int ntc = lin & (nbn - 1);
  const int bm  = mt << 7;
  const int bn  = ntc << 7;

  const __bf16* Ab = A  + (size_t)bm * K;
  const __bf16* Bb = Bt + (size_t)bn * K;
  const int nk = K >> 5;

  f32x4 acc[4][4];
  #pragma unroll
  for (int i = 0; i < 4; ++i)
    #pragma unroll
    for (int j = 0; j < 4; ++j) acc[i][j] = (f32x4){0.f, 0.f, 0.f, 0.f};

  // staging: LDS lane-linear (gload_lds requirement); global col-chunk pre-swizzled so
  // swizzled frag reads see linear data (rule 21): LDS[r][sl] = G[r][sl ^ ((r>>1)&3)].
  #define STG(P, gb, tile, buf, k2) {                                           \
    const int ch_ = tid + ((k2) << 8);                                          \
    const int r_ = ch_ >> 2, c_ = ch_ & 3;                                      \
    gload16(gb + (size_t)r_ * K + ((tile) << 5) + ((c_ ^ ((r_ >> 1) & 3)) << 3),\
            &P[buf][ch_ << 3]);                                                 \
  }

  // prologue: stage tiles 0,1 (8 loads); vmcnt(4) leaves tile1's 4 in flight
  STG(Asm, Ab, 0, 0, 0) STG(Asm, Ab, 0, 0, 1)
  STG(Bsm, Bb, 0, 0, 0) STG(Bsm, Bb, 0, 0, 1)
  STG(Asm, Ab, 1, 1, 0) STG(Asm, Ab, 1, 1, 1)
  STG(Bsm, Bb, 1, 1, 0) STG(Bsm, Bb, 1, 1, 1)
  wait_vm4();
  __builtin_amdgcn_s_barrier();

  int cur = 0;
  for (int t = 0; t < nk; ++t) {
    const int nx2 = (cur == 0) ? 2 : cur - 1;    // (cur+2)%3 : buffer for tile t+2
    const bool st = (t + 2 < nk);

    // issue next-next tile's loads FIRST (max latency cover)
    if (st) {
      STG(Asm, Ab, t + 2, nx2, 0) STG(Asm, Ab, t + 2, nx2, 1)
      STG(Bsm, Bb, t + 2, nx2, 0) STG(Bsm, Bb, t + 2, nx2, 1)
    }

    bf16x8 af[4], bfr[4];
    #pragma unroll
    for (int i = 0; i < 4; ++i) {
      const int m = wm + i * 16 + l16;
      af[i] = *(const bf16x8*)(&Asm[cur][m * 32 + ((quad ^ ((m >> 1) & 3)) << 3)]);
    }
    #pragma unroll
    for (int j = 0; j < 4; ++j) {
      const int n = wn + j * 16 + l16;
      bfr[j] = *(const bf16x8*)(&Bsm[cur][n * 32 + ((quad ^ ((n >> 1) & 3)) << 3)]);
    }

    __builtin_amdgcn_s_setprio(1);
    #pragma unroll
    for (int i = 0; i < 4; ++i)
      #pragma unroll
      for (int j = 0; j < 4; ++j)
        acc[i][j] = __builtin_amdgcn_mfma_f32_16x16x32_bf16(af[i], bfr[j], acc[i][j], 0, 0, 0);
    __builtin_amdgcn_s_setprio(0);

    // tile end: counted wait (tile t+1 landed; tile t+2's 4 loads stay in flight)
    if (st) { wait_vm4(); } else { wait_vm0(); }
    __builtin_amdgcn_s_barrier();
    cur = (cur == 2) ? 0 : cur + 1;
  }
  #undef STG

  // ---- epilogue. C/D layout: col = lane&15, row = quad*4 + reg  [m89-verified] ----
  if (epi == 1) {
    // full-line bf16 path: scatter through per-wave LDS [64][72] bf16 (stride 144B),
    // read back bf16x8 -> 16B/lane stores; each wave-store covers full 64B lines.
    const bool dosig = (bn >= 512);
    __bf16* dst = dosig ? C1 : C1b;
    const int cb = dosig ? (bn - 512) : bn;
    char* wb = (char*)Asm + w * 9216;            // 4 waves x 9216 B <= 24 KB (ring free)
    #pragma unroll
    for (int i = 0; i < 4; ++i)
      #pragma unroll
      for (int j = 0; j < 4; ++j) {
        const float bv = bias[bn + wn + j * 16 + l16];
        #pragma unroll
        for (int r = 0; r < 4; ++r) {
          float v = acc[i][j][r] + bv;
          if (dosig) v = 1.f / (1.f + expf(-v));
          *(__bf16*)(wb + (i * 16 + quad * 4 + r) * 144 + (j * 16 + l16) * 2) = (__bf16)v;
        }
      }
    wait_lgkm0();                                 // wave-local; no barrier needed
    #pragma unroll
    for (int i = 0; i < 4; ++i)
      #pragma unroll
      for (int h = 0; h < 2; ++h) {
        const int rr = (lane >> 3) + h * 8;       // 0..15 within i-block
        bf16x8 vv = *(bf16x8*)(wb + (i * 16 + rr) * 144 + (lane & 7) * 16);
        const int grow = bm + wm + i * 16 + rr;
        *(bf16x8*)(dst + (size_t)grow * 512 + cb + wn + (lane & 7) * 8) = vv;
      }
  } else {
    // fp32 path: 16 lanes x 4B = full 64B line per store group already
    #pragma unroll
    for (int j = 0; j < 4; ++j) {
      const int col = wn + j * 16 + l16;
      const float bv = bias[bn + col];
      #pragma unroll
      for (int i = 0; i < 4; ++i) {
        const int row0 = bm + wm + i * 16 + quad * 4;
        #pragma unroll
        for (int r = 0; r < 4; ++r) {
          float v = acc[i][j][r] + bv;
          size_t off = (size_t)(row0 + r) * N + bn + col;
          if (epi == 2) v += res[off];
          C0[off] = v;
        }
      }
    }
  }
}

// ---------------- fp32 -> bf16 elementwise (tokens) ----------------
__global__ __launch_bounds__(256) void cvt_k(const float* __restrict__ s, __bf16* __restrict__ d)
{
  size_t i = ((size_t)blockIdx.x * 256 + threadIdx.x) * 8;
  float4 a = *(const float4*)(s + i);
  float4 b = *(const float4*)(s + i + 4);
  bf16x8 v;
  v[0] = (__bf16)a.x; v[1] = (__bf16)a.y; v[2] = (__bf16)a.z; v[3] = (__bf16)a.w;
  v[4] = (__bf16)b.x; v[5] = (__bf16)b.y; v[6] = (__bf16)b.z; v[7] = (__bf16)b.w;
  *(bf16x8*)(d + i) = v;
}

// ---------------- transpose KxN fp32 -> NxK bf16 (weights) ----------------
__global__ __launch_bounds__(256) void tr_k(const float* __restrict__ src, __bf16* __restrict__ dst,
                                            int K, int N, size_t sstr, size_t dstr)
{
  __shared__ float t[32][33];
  const float* s = src + blockIdx.z * sstr;
  __bf16* d = dst + blockIdx.z * dstr;
  int n0 = blockIdx.x * 32, k0 = blockIdx.y * 32;
  int tx = threadIdx.x & 31, ty = threadIdx.x >> 5;   // 32x8
  #pragma unroll
  for (int i = 0; i < 4; ++i)
    t[ty + i * 8][tx] = s[(size_t)(k0 + ty + i * 8) * N + n0 + tx];
  __syncthreads();
  #pragma unroll
  for (int i = 0; i < 4; ++i)
    d[(size_t)(n0 + ty + i * 8) * K + k0 + tx] = (__bf16)t[tx][ty + i * 8];
}

// ---------------- LayerNorm over D=512, one wave per position, bf16 out ----------------
__global__ __launch_bounds__(256) void ln_k(const float* __restrict__ x, const float* __restrict__ w,
                                            const float* __restrict__ bv, __bf16* __restrict__ out)
{
  int gw = (blockIdx.x * 256 + threadIdx.x) >> 6;   // position
  int lane = threadIdx.x & 63;
  const float* xp = x + ((size_t)gw << 9) + lane * 8;
  float4 u0 = *(const float4*)xp;
  float4 u1 = *(const float4*)(xp + 4);
  float v[8] = {u0.x,u0.y,u0.z,u0.w,u1.x,u1.y,u1.z,u1.w};
  float s = 0.f;
  #pragma unroll
  for (int j = 0; j < 8; ++j) s += v[j];
  #pragma unroll
  for (int off = 32; off; off >>= 1) s += __shfl_xor(s, off, 64);
  float mu = s * (1.f/512.f);
  float q = 0.f;
  #pragma unroll
  for (int j = 0; j < 8; ++j) { float d = v[j] - mu; q += d*d; }
  #pragma unroll
  for (int off = 32; off; off >>= 1) q += __shfl_xor(q, off, 64);
  float rstd = rsqrtf(q * (1.f/512.f) + 1e-5f);
  int dch = lane * 8;
  float4 w0 = *(const float4*)(w + dch),  w1 = *(const float4*)(w + dch + 4);
  float4 b0 = *(const float4*)(bv + dch), b1 = *(const float4*)(bv + dch + 4);
  float wv[8] = {w0.x,w0.y,w0.z,w0.w,w1.x,w1.y,w1.z,w1.w};
  float bb[8] = {b0.x,b0.y,b0.z,b0.w,b1.x,b1.y,b1.z,b1.w};
  bf16x8 ov;
  #pragma unroll
  for (int j = 0; j < 8; ++j) ov[j] = (__bf16)((v[j] - mu) * rstd * wv[j] + bb[j]);
  *(bf16x8*)(out + ((size_t)gw << 9) + dch) = ov;
}

// ================= Fully-fused conv + 2D scan, 16 ch/block, 2 blocks/CU =================
// R4: R3 counters showed scan2d 1 block/CU (144KB LDS), Occ 18%, VALU 50%, HBM 14% ->
// latency-bound with no co-resident block. Halve channels/block (32->16): LDS 76KB ->
// 2 blocks/CU; each thread owns ONE chunk (same total work, 2x blocks). Chunk-major
// padded LDS [32 chunk][32 pos][16 ch], chunk stride 544 el: row reads 2-way aliased
// (free, m136), col reads conflict-free (stride 272 dw === 16 mod 32). XCD swizzle
// cg = (bx&7)*4 + bx>>3: the 4 cgs sharing a 128B global line land on one XCD -> L2
// merges the 32B segments (FETCH/WRITE stay ideal).
__device__ __forceinline__ float sig_a(float al) {
  float a = 1.f / (1.f + expf(-al));
  return fminf(fmaxf(a, 1e-4f), 1.f - 1e-4f);
}

#define CST 544   // chunk stride in elements: 32*16 + 32 pad (1088 B)

__global__ __launch_bounds__(512, 4) void scan2d_k(
    const __bf16* __restrict__ xin, const float* __restrict__ cw, const float* __restrict__ cb,
    const float* __restrict__ alog, const float* __restrict__ bvec, const float* __restrict__ cvec,
    const float* __restrict__ dvec, const __bf16* __restrict__ gate, __bf16* __restrict__ yo)
{
  __shared__ __bf16 T[32 * CST];    // xin tile; partial park in phase C. 34 KB
  __shared__ __bf16 Y[32 * CST];    // u tile. 34 KB
  __shared__ float  S[4][32][16];   // chunk sums: rowF,rowB,colF,colB. 8 KB
  const int tid = threadIdx.x;
  const int bx  = blockIdx.x;
  const int cg  = ((bx & 7) << 2) | (bx >> 3);   // channel group of 16; line-mates same XCD
  const int b   = blockIdx.y;
  const int ch  = tid & 15;
  const int c0  = tid >> 4;         // 0..31; thread owns chunk c0
  const int d   = (cg << 4) + ch;

  const float a   = sig_a(alog[d]);
  const float lna = logf(a);
  const float ia  = 1.f / a;
  const float bb  = bvec[d];
  const float sc  = 0.25f * cvec[d];
  const float dd  = dvec[d];

  const __bf16* ub = xin + ((size_t)b << 19) + (cg << 4);

  // ---- load xin tile: 4 x bf16x8 per thread, 16 B/lane ----
  #pragma unroll
  for (int i = 0; i < 4; ++i) {
    int f = tid + i * 512;          // 16B chunk id, 0..2047
    int pos = f >> 1, half = f & 1;
    *(bf16x8*)(T + (pos >> 5) * CST + ((pos & 31) << 4) + (half << 3))
        = *(const bf16x8*)(ub + (size_t)pos * 512 + (half << 3));
  }
  // conv weights while loads are in flight
  float w00 = cw[(0 << 9) + d], w01 = cw[(1 << 9) + d], w02 = cw[(2 << 9) + d];
  float w10 = cw[(3 << 9) + d], w11 = cw[(4 << 9) + d], w12 = cw[(5 << 9) + d];
  float w20 = cw[(6 << 9) + d], w21 = cw[(7 << 9) + d], w22 = cw[(8 << 9) + d];
  const float cbv = cb[d];
  // scan bases (loop-invariant; direct expf avoids 0*inf at extreme a)
  const float A0f = expf((float)(c0 << 5) * lna),        R0f = expf((float)(c0 << 5) * -lna);
  const float A0b = expf((float)((31 - c0) << 5) * lna), R0b = expf((float)((31 - c0) << 5) * -lna);
  __syncthreads();

  // ---- phase 0: depthwise 3x3 conv + SiLU, row c0 -> Y ----
  {
    const bool up = (c0 > 0);
    const bool dn = (c0 < 31);
    float a0 = 0.f, a1 = 0.f, a2 = 0.f;                                  // col -1
    float b0 = up ? (float)T[(c0 - 1) * CST + ch] : 0.f;                 // col 0
    float b1 =      (float)T[c0 * CST + ch];
    float b2 = dn ? (float)T[(c0 + 1) * CST + ch] : 0.f;
    #pragma unroll 4
    for (int ww = 0; ww < 32; ++ww) {
      float e0 = 0.f, e1 = 0.f, e2 = 0.f;                                // col ww+1
      if (ww < 31) {
        e0 = up ? (float)T[(c0 - 1) * CST + ((ww + 1) << 4) + ch] : 0.f;
        e1 =      (float)T[c0 * CST + ((ww + 1) << 4) + ch];
        e2 = dn ? (float)T[(c0 + 1) * CST + ((ww + 1) << 4) + ch] : 0.f;
      }
      float acc0 = cbv;
      acc0 = fmaf(a0, w00, acc0); acc0 = fmaf(b0, w01, acc0); acc0 = fmaf(e0, w02, acc0);
      acc0 = fmaf(a1, w10, acc0); acc0 = fmaf(b1, w11, acc0); acc0 = fmaf(e1, w12, acc0);
      acc0 = fmaf(a2, w20, acc0); acc0 = fmaf(b2, w21, acc0); acc0 = fmaf(e2, w22, acc0);
      acc0 = acc0 / (1.f + expf(-acc0));
      Y[c0 * CST + (ww << 4) + ch] = (__bf16)acc0;
      a0 = b0; a1 = b1; a2 = b2; b0 = e0; b1 = e1; b2 = e2;
    }
  }
  __syncthreads();

  // one scan step: r += u*bb/max(apr,1e-20) with tracked reciprocal
  #define STEP(r_, uu_, apr_, rp_)                                 \
    { float rr_ = (apr_ < 1e-20f) ? 1e20f : rp_;                   \
      r_ = fmaf((uu_) * bb, rr_, r_); }

  // ---- phase A: 4 chunk sums (rowF/rowB/colF/colB) in one loop ----
  {
    float pf = A0f, qf = R0f, pb = A0b, qb = R0b;
    float s0 = 0.f, s1 = 0.f, s2 = 0.f, s3 = 0.f;
    #pragma unroll 4
    for (int j = 0; j < 32; ++j) {
      float urf = (float)Y[c0 * CST + (j << 4) + ch];
      float urb = (float)Y[c0 * CST + ((31 - j) << 4) + ch];
      float ucf = (float)Y[j * CST + (c0 << 4) + ch];
      float ucb = (float)Y[(31 - j) * CST + (c0 << 4) + ch];
      STEP(s0, urf, pf, qf)  STEP(s2, ucf, pf, qf)
      STEP(s1, urb, pb, qb)  STEP(s3, ucb, pb, qb)
      pf *= a; qf *= ia; pb *= a; qb *= ia;
    }
    S[0][c0][ch] = s0; S[1][c0][ch] = s1; S[2][c0][ch] = s2; S[3][c0][ch] = s3;
  }
  __syncthreads();

  // ---- phase B: exclusive prefix (F arrays) / exclusive suffix (B arrays) ----
  if (tid < 64) {
    int arr = tid >> 4, ch2 = tid & 15;
    float run = 0.f;
    if ((arr & 1) == 0) {
      #pragma unroll 4
      for (int cc = 0; cc < 32; ++cc) { float v = S[arr][cc][ch2]; S[arr][cc][ch2] = run; run += v; }
    } else {
      #pragma unroll 4
      for (int cc = 31; cc >= 0; --cc) { float v = S[arr][cc][ch2]; S[arr][cc][ch2] = run; run += v; }
    }
  }
  __syncthreads();

  // ---- C-col fwd: raw partial -> T  (column c0: pos = j*32+c0 -> chunk j, in-chunk c0) ----
  {
    float r = S[2][c0][ch];
    float p = A0f, q = R0f;
    #pragma unroll 4
    for (int j = 0; j < 32; ++j) {
      int i0 = j * CST + (c0 << 4) + ch;
      float u = (float)Y[i0];
      float ap = fmaxf(p, 1e-20f);
      STEP(r, u, p, q)
      T[i0] = (__bf16)(r * ap);
      p *= a; q *= ia;
    }
  }
  // ---- C-col bwd: T = sc*(T + r*ap)  [same-thread RMW] ----
  {
    float r = S[3][c0][ch];
    float p = A0b, q = R0b;
    #pragma unroll 4
    for (int j = 31; j >= 0; --j) {
      int i0 = j * CST + (c0 << 4) + ch;
      float u = (float)Y[i0];
      float ap = fmaxf(p, 1e-20f);
      STEP(r, u, p, q)
      T[i0] = (__bf16)(sc * ((float)T[i0] + r * ap));
      p *= a; q *= ia;
    }
  }
  __syncthreads();   // row threads read other threads' col finals

  // ---- C-row fwd: T += sc*(r*ap)  (row c0: chunk c0, in-chunk j) ----
  {
    float r = S[0][c0][ch];
    float p = A0f, q = R0f;
    #pragma unroll 4
    for (int j = 0; j < 32; ++j) {
      int i0 = c0 * CST + (j << 4) + ch;
      float u = (float)Y[i0];
      float ap = fmaxf(p, 1e-20f);
      STEP(r, u, p, q)
      T[i0] = (__bf16)((float)T[i0] + sc * (r * ap));
      p *= a; q *= ia;
    }
  }
  // ---- C-row bwd: finalize + d*u, *gate, write out ----
  {
    const __bf16* gb = gate + ((size_t)b << 19) + (cg << 4) + ch;
    __bf16* yb = yo + ((size_t)b << 19) + (cg << 4) + ch;
    float r = S[1][c0][ch];
    float p = A0b, q = R0b;
    #pragma unroll 4
    for (int j = 31; j >= 0; --j) {
      int pp = (c0 << 5) + j;
      int i0 = c0 * CST + (j << 4) + ch;
      float u = (float)Y[i0];
      float ap = fmaxf(p, 1e-20f);
      STEP(r, u, p, q)
      float y0 = (float)T[i0] + sc * (r * ap) + dd * u;
      yb[(size_t)pp * 512] = (__bf16)(y0 * (float)gb[(size_t)pp * 512]);
      p *= a; q *= ia;
    }
  }
  #undef STEP
}

// ---------------- mean over 1024 positions (bf16 in) -> (16, 512) fp32 ----------------
__global__ __launch_bounds__(256) void reduce_k(const __bf16* __restrict__ hn, float* __restrict__ out)
{
  __shared__ float part[4][64];
  int l = threadIdx.x & 63;       // channel within group
  int q = threadIdx.x >> 6;       // position quarter
  int d = blockIdx.y * 64 + l;
  int b = blockIdx.x;
  const __bf16* p = hn + ((size_t)b << 19) + d + ((size_t)(q * 256) << 9);
  float s0 = 0.f, s1 = 0.f, s2 = 0.f, s3 = 0.f;
  for (int t = 0; t < 256; t += 4) {
    s0 += (float)p[(size_t)(t+0) << 9];
    s1 += (float)p[(size_t)(t+1) << 9];
    s2 += (float)p[(size_t)(t+2) << 9];
    s3 += (float)p[(size_t)(t+3) << 9];
  }
  part[q][l] = (s0 + s1) + (s2 + s3);
  __syncthreads();
  if (threadIdx.x < 64)
    out[b * 512 + d] = (part[0][l] + part[1][l] + part[2][l] + part[3][l]) * (1.f / 1024.f);
}

extern "C" void kernel_launch(void* const* d_in, const int* in_sizes, int n_in,
                              void* d_out, int out_size, void* d_ws, size_t ws_size,
                              hipStream_t stream)
{
  const float* tokens = (const float*)d_in[0];
  const float* in_w   = (const float*)d_in[1];
  const float* in_b   = (const float*)d_in[2];
  const float* nw     = (const float*)d_in[3];
  const float* nb     = (const float*)d_in[4];
  const float* iw     = (const float*)d_in[5];
  const float* ib     = (const float*)d_in[6];
  const float* cw     = (const float*)d_in[7];
  const float* cb     = (const float*)d_in[8];
  const float* al     = (const float*)d_in[9];
  const float* bbv    = (const float*)d_in[10];
  const float* ccv    = (const float*)d_in[11];
  const float* ddv    = (const float*)d_in[12];
  const float* ow     = (const float*)d_in[13];
  const float* obv    = (const float*)d_in[14];
  const float* onw    = (const float*)d_in[15];
  const float* onb    = (const float*)d_in[16];

  // workspace layout (~115 MB):
  float*  x     = (float*)d_ws;                      // fp32 residual (33.5 MB)
  __bf16* hy16  = (__bf16*)(x + PP);                 // bf16 h / yg / final-ln (16.8 MB)
  __bf16* xin16 = hy16 + PP;                         // bf16 x_in (16.8 MB)
  __bf16* g16   = xin16 + PP;                        // bf16 gate (16.8 MB)
  __bf16* iwT   = g16 + PP;                          // 4x(1024x512) bf16 (4.2 MB)
  __bf16* owT   = iwT + (size_t)4 * 1024 * 512;      // 4x(512x512) bf16 (2.1 MB)
  __bf16* tb16  = owT + (size_t)4 * 512 * 512;       // tokens bf16 (25.2 MB)
  __bf16* inwT  = xin16;                             // in_proj_w^T bf16 (pre-loop alias)

  // --- weight/input conversion (once per launch) ---
  cvt_k<<<6144, 256, 0, stream>>>(tokens, tb16);
  tr_k<<<dim3(16, 24, 1), 256, 0, stream>>>(in_w, inwT, 768, 512, 0, 0);
  tr_k<<<dim3(32, 16, 4), 256, 0, stream>>>(iw, iwT, 512, 1024, (size_t)512*1024, (size_t)1024*512);
  tr_k<<<dim3(16, 16, 4), 256, 0, stream>>>(ow, owT, 512, 512, (size_t)512*512, (size_t)512*512);

  // x = tokens @ in_proj_w + b   (128 M-tiles x 4 N-tiles = 512 blocks, 2/CU)
  gemm_k<<<512, 256, 0, stream>>>(tb16, inwT, in_b, nullptr, x, nullptr, nullptr,
                                  512, 768, 0);

  for (int i = 0; i < 4; ++i) {
    ln_k<<<4096, 256, 0, stream>>>(x, nw + i*512, nb + i*512, hy16);
    // (h @ iw + ib): 128 x 8 = 1024 blocks, 3/CU resident
    gemm_k<<<1024, 256, 0, stream>>>(hy16, iwT + (size_t)i*1024*512, ib + i*1024,
                                     nullptr, nullptr, g16, xin16, 1024, 512, 1);
    // 32 ch-groups x 16 batch = 512 blocks, 2/CU
    scan2d_k<<<dim3(32, 16), 512, 0, stream>>>(xin16, cw + i*9*512, cb + i*512,
                                               al + i*512, bbv + i*512, ccv + i*512,
                                               ddv + i*512, g16, hy16);
    // (yg @ ow + ob + x): 128 x 4 = 512 blocks
    gemm_k<<<512, 256, 0, stream>>>(hy16, owT + (size_t)i*512*512, obv + i*512,
                                    x, x, nullptr, nullptr, 512, 512, 2);
  }

  ln_k<<<4096, 256, 0, stream>>>(x, onw, onb, hy16);
  reduce_k<<<dim3(16, 8), 256, 0, stream>>>(hy16, (float*)d_out);
}

// Round 5
// 535.751 us; speedup vs baseline: 1.2645x; 1.1292x over previous
//
#include <hip/hip_runtime.h>
#include <hip/hip_bf16.h>
#include <math.h>

#define NPOS 16384   // B*H*W = 16*32*32
#define DD   512
#define PP   ((size_t)NPOS * DD)   // 8388608 elements per plane

typedef __bf16 bf16x8 __attribute__((ext_vector_type(8)));
typedef float  f32x4  __attribute__((ext_vector_type(4)));

// ---- async global->LDS, 16B per lane (global_load_lds_dwordx4) ----
__device__ __forceinline__ void gload16(const __bf16* g, __bf16* l) {
  __builtin_amdgcn_global_load_lds((__attribute__((address_space(1))) void*)(g),
                                   (__attribute__((address_space(3))) void*)(l), 16, 0, 0);
}
__device__ __forceinline__ void wait_vm0() { asm volatile("s_waitcnt vmcnt(0)" ::: "memory"); }
__device__ __forceinline__ void wait_vm2() { asm volatile("s_waitcnt vmcnt(2)" ::: "memory"); }
__device__ __forceinline__ void wait_lgkm0() { asm volatile("s_waitcnt lgkmcnt(0)" ::: "memory"); }

// ================= bf16 MFMA GEMM, 128x128 / 8 waves / 3-deep gload_lds ring =================
// R5: R4 counters (epi1 43.6us, MfmaUtil 14, VALU 25, HBM 14, Occ 18.7, identical ~43us
// across three K-loop schedules) -> LATENCY-bound at 8-12 waves/CU. Fix = occupancy:
// 512 thr / 8 waves (2M x 4N, 64x32 per wave, 8 MFMA/tile, acc[4][2]); LDS still 48KB
// -> 3 blocks/CU for 1024-block grids (24 waves/CU = 75%), 2 for 512-block (50%).
//   * staging: ONE global_load_lds per plane per tile (512 lanes x 16B = 128x32 tile);
//     3-deep ring, counted s_waitcnt vmcnt(2) at tile end (t+1 landed, t+2 in flight).
//   * Global-side XOR swizzle (c ^ ((row>>1)&3)): frag ds_read_b128 conflict-free.
//   * epi1 (bf16 out): full-line epilogue via per-wave LDS shuffle (64 rows x 80B),
//     bf16x8 stores, full 64B lines. epi0/2 (fp32): direct stores = full lines.
// Grid: 1-D, bijective XCD swizzle (nwg % 8 == 0); ntc fastest -> A-sharers same XCD.
// epi 0: C0 fp32 (ld N) = acc + bias
// epi 1: N=1024; bn<512 -> C1b bf16 (ld 512); bn>=512 -> sigmoid -> C1 bf16 (ld 512)
// epi 2: C0 fp32 (ld N) = acc + bias + res
__global__ __launch_bounds__(512, 4) void gemm_k(
    const __bf16* __restrict__ A, const __bf16* __restrict__ Bt,
    const float* __restrict__ bias, const float* __restrict__ res,
    float* __restrict__ C0, __bf16* __restrict__ C1, __bf16* __restrict__ C1b,
    int N, int K, int epi)
{
  __shared__ __bf16 SM[3 * 4096 * 2];   // 48 KB: A ring [3][4096] then B ring [3][4096]
  __bf16 (*Asm)[4096] = (__bf16(*)[4096])SM;
  __bf16 (*Bsm)[4096] = (__bf16(*)[4096])(SM + 3 * 4096);

  const int tid  = threadIdx.x;
  const int w    = tid >> 6;
  const int lane = tid & 63;
  const int quad = lane >> 4;
  const int l16  = lane & 15;
  const int wm   = (w >> 2) << 6;       // 2 M-waves x 64 rows
  const int wn   = (w & 3) << 5;        // 4 N-waves x 32 cols

  // grid decode: bijective XCD swizzle, then ntc fastest (A-sharers adjacent per XCD)
  const int nwg = gridDim.x;
  const int cpx = nwg >> 3;
  const int lin = (blockIdx.x & 7) * cpx + (blockIdx.x >> 3);
  const int nbn = N >> 7;               // 128-wide N tiles (4 or 8)
  const int sh  = (nbn == 8) ? 3 : 2;
  const int mt  = lin >> sh;
  const int ntc = lin & (nbn - 1);
  const int bm  = mt << 7;
  const int bn  = ntc << 7;

  const __bf16* Ab = A  + (size_t)bm * K;
  const __bf16* Bb = Bt + (size_t)bn * K;
  const int nk = K >> 5;

  f32x4 acc[4][2];
  #pragma unroll
  for (int i = 0; i < 4; ++i)
    #pragma unroll
    for (int j = 0; j < 2; ++j) acc[i][j] = (f32x4){0.f, 0.f, 0.f, 0.f};

  // staging: 512 threads x 16B = one 128x32 tile per instruction. LDS lane-linear
  // (gload_lds requirement); global col-chunk pre-swizzled so swizzled frag reads see
  // linear data (rule 21): LDS[r][sl] = G[r][sl ^ ((r>>1)&3)].
  #define STG(P, gb, tile, buf) {                                               \
    const int r_ = tid >> 2, c_ = tid & 3;                                      \
    gload16(gb + (size_t)r_ * K + ((tile) << 5) + ((c_ ^ ((r_ >> 1) & 3)) << 3),\
            &P[buf][tid << 3]);                                                 \
  }

  // prologue: stage tiles 0,1 (4 loads); vmcnt(2) leaves tile1's 2 in flight
  STG(Asm, Ab, 0, 0) STG(Bsm, Bb, 0, 0)
  STG(Asm, Ab, 1, 1) STG(Bsm, Bb, 1, 1)
  wait_vm2();
  __builtin_amdgcn_s_barrier();

  int cur = 0;
  for (int t = 0; t < nk; ++t) {
    const int nx2 = (cur == 0) ? 2 : cur - 1;    // (cur+2)%3 : buffer for tile t+2
    const bool st = (t + 2 < nk);

    // issue next-next tile's loads FIRST (max latency cover; target buffer was fully
    // read in tile t-1, barrier-ordered)
    if (st) {
      STG(Asm, Ab, t + 2, nx2)
      STG(Bsm, Bb, t + 2, nx2)
    }

    bf16x8 af[4], bfr[2];
    #pragma unroll
    for (int i = 0; i < 4; ++i) {
      const int m = wm + i * 16 + l16;
      af[i] = *(const bf16x8*)(&Asm[cur][m * 32 + ((quad ^ ((m >> 1) & 3)) << 3)]);
    }
    #pragma unroll
    for (int j = 0; j < 2; ++j) {
      const int n = wn + j * 16 + l16;
      bfr[j] = *(const bf16x8*)(&Bsm[cur][n * 32 + ((quad ^ ((n >> 1) & 3)) << 3)]);
    }

    __builtin_amdgcn_s_setprio(1);
    #pragma unroll
    for (int i = 0; i < 4; ++i)
      #pragma unroll
      for (int j = 0; j < 2; ++j)
        acc[i][j] = __builtin_amdgcn_mfma_f32_16x16x32_bf16(af[i], bfr[j], acc[i][j], 0, 0, 0);
    __builtin_amdgcn_s_setprio(0);

    // tile end: counted wait (tile t+1 landed; tile t+2's 2 loads stay in flight)
    if (st) { wait_vm2(); } else { wait_vm0(); }
    __builtin_amdgcn_s_barrier();
    cur = (cur == 2) ? 0 : cur + 1;
  }
  #undef STG

  // ---- epilogue. C/D layout: col = lane&15, row = quad*4 + reg  [m89-verified] ----
  if (epi == 1) {
    // full-line bf16 path: scatter through per-wave LDS (64 rows x 80B stride), read
    // back bf16x8 -> 16B/lane stores; each 4-lane group covers a full 64B line.
    const bool dosig = (bn >= 512);
    __bf16* dst = dosig ? C1 : C1b;
    const int cb = dosig ? (bn - 512) : bn;
    char* wb = (char*)SM + w * 5120;             // 8 waves x 5120 B = 40 KB <= 48 KB
    #pragma unroll
    for (int i = 0; i < 4; ++i)
      #pragma unroll
      for (int j = 0; j < 2; ++j) {
        const float bv = bias[bn + wn + j * 16 + l16];
        #pragma unroll
        for (int r = 0; r < 4; ++r) {
          float v = acc[i][j][r] + bv;
          if (dosig) v = 1.f / (1.f + expf(-v));
          *(__bf16*)(wb + (i * 16 + quad * 4 + r) * 80 + (j * 16 + l16) * 2) = (__bf16)v;
        }
      }
    wait_lgkm0();                                 // wave-local; no barrier needed
    #pragma unroll
    for (int s = 0; s < 4; ++s) {
      const int rr = s * 16 + (lane >> 2);        // 0..63 within wave tile
      bf16x8 vv = *(bf16x8*)(wb + rr * 80 + (lane & 3) * 16);
      const int grow = bm + wm + rr;
      *(bf16x8*)(dst + (size_t)grow * 512 + cb + wn + (lane & 3) * 8) = vv;
    }
  } else {
    // fp32 path: 16 lanes x 4B = full 64B line per store group already
    #pragma unroll
    for (int j = 0; j < 2; ++j) {
      const int col = wn + j * 16 + l16;
      const float bv = bias[bn + col];
      #pragma unroll
      for (int i = 0; i < 4; ++i) {
        const int row0 = bm + wm + i * 16 + quad * 4;
        #pragma unroll
        for (int r = 0; r < 4; ++r) {
          float v = acc[i][j][r] + bv;
          size_t off = (size_t)(row0 + r) * N + bn + col;
          if (epi == 2) v += res[off];
          C0[off] = v;
        }
      }
    }
  }
}

// ---------------- fp32 -> bf16 elementwise (tokens) ----------------
__global__ __launch_bounds__(256) void cvt_k(const float* __restrict__ s, __bf16* __restrict__ d)
{
  size_t i = ((size_t)blockIdx.x * 256 + threadIdx.x) * 8;
  float4 a = *(const float4*)(s + i);
  float4 b = *(const float4*)(s + i + 4);
  bf16x8 v;
  v[0] = (__bf16)a.x; v[1] = (__bf16)a.y; v[2] = (__bf16)a.z; v[3] = (__bf16)a.w;
  v[4] = (__bf16)b.x; v[5] = (__bf16)b.y; v[6] = (__bf16)b.z; v[7] = (__bf16)b.w;
  *(bf16x8*)(d + i) = v;
}

// ---------------- transpose KxN fp32 -> NxK bf16 (weights) ----------------
__global__ __launch_bounds__(256) void tr_k(const float* __restrict__ src, __bf16* __restrict__ dst,
                                            int K, int N, size_t sstr, size_t dstr)
{
  __shared__ float t[32][33];
  const float* s = src + blockIdx.z * sstr;
  __bf16* d = dst + blockIdx.z * dstr;
  int n0 = blockIdx.x * 32, k0 = blockIdx.y * 32;
  int tx = threadIdx.x & 31, ty = threadIdx.x >> 5;   // 32x8
  #pragma unroll
  for (int i = 0; i < 4; ++i)
    t[ty + i * 8][tx] = s[(size_t)(k0 + ty + i * 8) * N + n0 + tx];
  __syncthreads();
  #pragma unroll
  for (int i = 0; i < 4; ++i)
    d[(size_t)(n0 + ty + i * 8) * K + k0 + tx] = (__bf16)t[tx][ty + i * 8];
}

// ---------------- LayerNorm over D=512, one wave per position, bf16 out ----------------
__global__ __launch_bounds__(256) void ln_k(const float* __restrict__ x, const float* __restrict__ w,
                                            const float* __restrict__ bv, __bf16* __restrict__ out)
{
  int gw = (blockIdx.x * 256 + threadIdx.x) >> 6;   // position
  int lane = threadIdx.x & 63;
  const float* xp = x + ((size_t)gw << 9) + lane * 8;
  float4 u0 = *(const float4*)xp;
  float4 u1 = *(const float4*)(xp + 4);
  float v[8] = {u0.x,u0.y,u0.z,u0.w,u1.x,u1.y,u1.z,u1.w};
  float s = 0.f;
  #pragma unroll
  for (int j = 0; j < 8; ++j) s += v[j];
  #pragma unroll
  for (int off = 32; off; off >>= 1) s += __shfl_xor(s, off, 64);
  float mu = s * (1.f/512.f);
  float q = 0.f;
  #pragma unroll
  for (int j = 0; j < 8; ++j) { float d = v[j] - mu; q += d*d; }
  #pragma unroll
  for (int off = 32; off; off >>= 1) q += __shfl_xor(q, off, 64);
  float rstd = rsqrtf(q * (1.f/512.f) + 1e-5f);
  int dch = lane * 8;
  float4 w0 = *(const float4*)(w + dch),  w1 = *(const float4*)(w + dch + 4);
  float4 b0 = *(const float4*)(bv + dch), b1 = *(const float4*)(bv + dch + 4);
  float wv[8] = {w0.x,w0.y,w0.z,w0.w,w1.x,w1.y,w1.z,w1.w};
  float bb[8] = {b0.x,b0.y,b0.z,b0.w,b1.x,b1.y,b1.z,b1.w};
  bf16x8 ov;
  #pragma unroll
  for (int j = 0; j < 8; ++j) ov[j] = (__bf16)((v[j] - mu) * rstd * wv[j] + bb[j]);
  *(bf16x8*)(out + ((size_t)gw << 9) + dch) = ov;
}

// ================= Fully-fused conv + 2D scan, 16 ch/block, 2 blocks/CU (R4-proven) =================
__device__ __forceinline__ float sig_a(float al) {
  float a = 1.f / (1.f + expf(-al));
  return fminf(fmaxf(a, 1e-4f), 1.f - 1e-4f);
}

#define CST 544   // chunk stride in elements: 32*16 + 32 pad (1088 B)

__global__ __launch_bounds__(512, 4) void scan2d_k(
    const __bf16* __restrict__ xin, const float* __restrict__ cw, const float* __restrict__ cb,
    const float* __restrict__ alog, const float* __restrict__ bvec, const float* __restrict__ cvec,
    const float* __restrict__ dvec, const __bf16* __restrict__ gate, __bf16* __restrict__ yo)
{
  __shared__ __bf16 T[32 * CST];    // xin tile; partial park in phase C. 34 KB
  __shared__ __bf16 Y[32 * CST];    // u tile. 34 KB
  __shared__ float  S[4][32][16];   // chunk sums: rowF,rowB,colF,colB. 8 KB
  const int tid = threadIdx.x;
  const int bx  = blockIdx.x;
  const int cg  = ((bx & 7) << 2) | (bx >> 3);   // channel group of 16; line-mates same XCD
  const int b   = blockIdx.y;
  const int ch  = tid & 15;
  const int c0  = tid >> 4;         // 0..31; thread owns chunk c0
  const int d   = (cg << 4) + ch;

  const float a   = sig_a(alog[d]);
  const float lna = logf(a);
  const float ia  = 1.f / a;
  const float bb  = bvec[d];
  const float sc  = 0.25f * cvec[d];
  const float dd  = dvec[d];

  const __bf16* ub = xin + ((size_t)b << 19) + (cg << 4);

  // ---- load xin tile: 4 x bf16x8 per thread, 16 B/lane ----
  #pragma unroll
  for (int i = 0; i < 4; ++i) {
    int f = tid + i * 512;          // 16B chunk id, 0..2047
    int pos = f >> 1, half = f & 1;
    *(bf16x8*)(T + (pos >> 5) * CST + ((pos & 31) << 4) + (half << 3))
        = *(const bf16x8*)(ub + (size_t)pos * 512 + (half << 3));
  }
  // conv weights while loads are in flight
  float w00 = cw[(0 << 9) + d], w01 = cw[(1 << 9) + d], w02 = cw[(2 << 9) + d];
  float w10 = cw[(3 << 9) + d], w11 = cw[(4 << 9) + d], w12 = cw[(5 << 9) + d];
  float w20 = cw[(6 << 9) + d], w21 = cw[(7 << 9) + d], w22 = cw[(8 << 9) + d];
  const float cbv = cb[d];
  // scan bases (loop-invariant; direct expf avoids 0*inf at extreme a)
  const float A0f = expf((float)(c0 << 5) * lna),        R0f = expf((float)(c0 << 5) * -lna);
  const float A0b = expf((float)((31 - c0) << 5) * lna), R0b = expf((float)((31 - c0) << 5) * -lna);
  __syncthreads();

  // ---- phase 0: depthwise 3x3 conv + SiLU, row c0 -> Y ----
  {
    const bool up = (c0 > 0);
    const bool dn = (c0 < 31);
    float a0 = 0.f, a1 = 0.f, a2 = 0.f;                                  // col -1
    float b0 = up ? (float)T[(c0 - 1) * CST + ch] : 0.f;                 // col 0
    float b1 =      (float)T[c0 * CST + ch];
    float b2 = dn ? (float)T[(c0 + 1) * CST + ch] : 0.f;
    #pragma unroll 4
    for (int ww = 0; ww < 32; ++ww) {
      float e0 = 0.f, e1 = 0.f, e2 = 0.f;                                // col ww+1
      if (ww < 31) {
        e0 = up ? (float)T[(c0 - 1) * CST + ((ww + 1) << 4) + ch] : 0.f;
        e1 =      (float)T[c0 * CST + ((ww + 1) << 4) + ch];
        e2 = dn ? (float)T[(c0 + 1) * CST + ((ww + 1) << 4) + ch] : 0.f;
      }
      float acc0 = cbv;
      acc0 = fmaf(a0, w00, acc0); acc0 = fmaf(b0, w01, acc0); acc0 = fmaf(e0, w02, acc0);
      acc0 = fmaf(a1, w10, acc0); acc0 = fmaf(b1, w11, acc0); acc0 = fmaf(e1, w12, acc0);
      acc0 = fmaf(a2, w20, acc0); acc0 = fmaf(b2, w21, acc0); acc0 = fmaf(e2, w22, acc0);
      acc0 = acc0 / (1.f + expf(-acc0));
      Y[c0 * CST + (ww << 4) + ch] = (__bf16)acc0;
      a0 = b0; a1 = b1; a2 = b2; b0 = e0; b1 = e1; b2 = e2;
    }
  }
  __syncthreads();

  // one scan step: r += u*bb/max(apr,1e-20) with tracked reciprocal
  #define STEP(r_, uu_, apr_, rp_)                                 \
    { float rr_ = (apr_ < 1e-20f) ? 1e20f : rp_;                   \
      r_ = fmaf((uu_) * bb, rr_, r_); }

  // ---- phase A: 4 chunk sums (rowF/rowB/colF/colB) in one loop ----
  {
    float pf = A0f, qf = R0f, pb = A0b, qb = R0b;
    float s0 = 0.f, s1 = 0.f, s2 = 0.f, s3 = 0.f;
    #pragma unroll 4
    for (int j = 0; j < 32; ++j) {
      float urf = (float)Y[c0 * CST + (j << 4) + ch];
      float urb = (float)Y[c0 * CST + ((31 - j) << 4) + ch];
      float ucf = (float)Y[j * CST + (c0 << 4) + ch];
      float ucb = (float)Y[(31 - j) * CST + (c0 << 4) + ch];
      STEP(s0, urf, pf, qf)  STEP(s2, ucf, pf, qf)
      STEP(s1, urb, pb, qb)  STEP(s3, ucb, pb, qb)
      pf *= a; qf *= ia; pb *= a; qb *= ia;
    }
    S[0][c0][ch] = s0; S[1][c0][ch] = s1; S[2][c0][ch] = s2; S[3][c0][ch] = s3;
  }
  __syncthreads();

  // ---- phase B: exclusive prefix (F arrays) / exclusive suffix (B arrays) ----
  if (tid < 64) {
    int arr = tid >> 4, ch2 = tid & 15;
    float run = 0.f;
    if ((arr & 1) == 0) {
      #pragma unroll 4
      for (int cc = 0; cc < 32; ++cc) { float v = S[arr][cc][ch2]; S[arr][cc][ch2] = run; run += v; }
    } else {
      #pragma unroll 4
      for (int cc = 31; cc >= 0; --cc) { float v = S[arr][cc][ch2]; S[arr][cc][ch2] = run; run += v; }
    }
  }
  __syncthreads();

  // ---- C-col fwd: raw partial -> T  (column c0: pos = j*32+c0 -> chunk j, in-chunk c0) ----
  {
    float r = S[2][c0][ch];
    float p = A0f, q = R0f;
    #pragma unroll 4
    for (int j = 0; j < 32; ++j) {
      int i0 = j * CST + (c0 << 4) + ch;
      float u = (float)Y[i0];
      float ap = fmaxf(p, 1e-20f);
      STEP(r, u, p, q)
      T[i0] = (__bf16)(r * ap);
      p *= a; q *= ia;
    }
  }
  // ---- C-col bwd: T = sc*(T + r*ap)  [same-thread RMW] ----
  {
    float r = S[3][c0][ch];
    float p = A0b, q = R0b;
    #pragma unroll 4
    for (int j = 31; j >= 0; --j) {
      int i0 = j * CST + (c0 << 4) + ch;
      float u = (float)Y[i0];
      float ap = fmaxf(p, 1e-20f);
      STEP(r, u, p, q)
      T[i0] = (__bf16)(sc * ((float)T[i0] + r * ap));
      p *= a; q *= ia;
    }
  }
  __syncthreads();   // row threads read other threads' col finals

  // ---- C-row fwd: T += sc*(r*ap)  (row c0: chunk c0, in-chunk j) ----
  {
    float r = S[0][c0][ch];
    float p = A0f, q = R0f;
    #pragma unroll 4
    for (int j = 0; j < 32; ++j) {
      int i0 = c0 * CST + (j << 4) + ch;
      float u = (float)Y[i0];
      float ap = fmaxf(p, 1e-20f);
      STEP(r, u, p, q)
      T[i0] = (__bf16)((float)T[i0] + sc * (r * ap));
      p *= a; q *= ia;
    }
  }
  // ---- C-row bwd: finalize + d*u, *gate, write out ----
  {
    const __bf16* gb = gate + ((size_t)b << 19) + (cg << 4) + ch;
    __bf16* yb = yo + ((size_t)b << 19) + (cg << 4) + ch;
    float r = S[1][c0][ch];
    float p = A0b, q = R0b;
    #pragma unroll 4
    for (int j = 31; j >= 0; --j) {
      int pp = (c0 << 5) + j;
      int i0 = c0 * CST + (j << 4) + ch;
      float u = (float)Y[i0];
      float ap = fmaxf(p, 1e-20f);
      STEP(r, u, p, q)
      float y0 = (float)T[i0] + sc * (r * ap) + dd * u;
      yb[(size_t)pp * 512] = (__bf16)(y0 * (float)gb[(size_t)pp * 512]);
      p *= a; q *= ia;
    }
  }
  #undef STEP
}

// ---------------- mean over 1024 positions (bf16 in) -> (16, 512) fp32 ----------------
__global__ __launch_bounds__(256) void reduce_k(const __bf16* __restrict__ hn, float* __restrict__ out)
{
  __shared__ float part[4][64];
  int l = threadIdx.x & 63;       // channel within group
  int q = threadIdx.x >> 6;       // position quarter
  int d = blockIdx.y * 64 + l;
  int b = blockIdx.x;
  const __bf16* p = hn + ((size_t)b << 19) + d + ((size_t)(q * 256) << 9);
  float s0 = 0.f, s1 = 0.f, s2 = 0.f, s3 = 0.f;
  for (int t = 0; t < 256; t += 4) {
    s0 += (float)p[(size_t)(t+0) << 9];
    s1 += (float)p[(size_t)(t+1) << 9];
    s2 += (float)p[(size_t)(t+2) << 9];
    s3 += (float)p[(size_t)(t+3) << 9];
  }
  part[q][l] = (s0 + s1) + (s2 + s3);
  __syncthreads();
  if (threadIdx.x < 64)
    out[b * 512 + d] = (part[0][l] + part[1][l] + part[2][l] + part[3][l]) * (1.f / 1024.f);
}

extern "C" void kernel_launch(void* const* d_in, const int* in_sizes, int n_in,
                              void* d_out, int out_size, void* d_ws, size_t ws_size,
                              hipStream_t stream)
{
  const float* tokens = (const float*)d_in[0];
  const float* in_w   = (const float*)d_in[1];
  const float* in_b   = (const float*)d_in[2];
  const float* nw     = (const float*)d_in[3];
  const float* nb     = (const float*)d_in[4];
  const float* iw     = (const float*)d_in[5];
  const float* ib     = (const float*)d_in[6];
  const float* cw     = (const float*)d_in[7];
  const float* cb     = (const float*)d_in[8];
  const float* al     = (const float*)d_in[9];
  const float* bbv    = (const float*)d_in[10];
  const float* ccv    = (const float*)d_in[11];
  const float* ddv    = (const float*)d_in[12];
  const float* ow     = (const float*)d_in[13];
  const float* obv    = (const float*)d_in[14];
  const float* onw    = (const float*)d_in[15];
  const float* onb    = (const float*)d_in[16];

  // workspace layout (~115 MB):
  float*  x     = (float*)d_ws;                      // fp32 residual (33.5 MB)
  __bf16* hy16  = (__bf16*)(x + PP);                 // bf16 h / yg / final-ln (16.8 MB)
  __bf16* xin16 = hy16 + PP;                         // bf16 x_in (16.8 MB)
  __bf16* g16   = xin16 + PP;                        // bf16 gate (16.8 MB)
  __bf16* iwT   = g16 + PP;                          // 4x(1024x512) bf16 (4.2 MB)
  __bf16* owT   = iwT + (size_t)4 * 1024 * 512;      // 4x(512x512) bf16 (2.1 MB)
  __bf16* tb16  = owT + (size_t)4 * 512 * 512;       // tokens bf16 (25.2 MB)
  __bf16* inwT  = xin16;                             // in_proj_w^T bf16 (pre-loop alias)

  // --- weight/input conversion (once per launch) ---
  cvt_k<<<6144, 256, 0, stream>>>(tokens, tb16);
  tr_k<<<dim3(16, 24, 1), 256, 0, stream>>>(in_w, inwT, 768, 512, 0, 0);
  tr_k<<<dim3(32, 16, 4), 256, 0, stream>>>(iw, iwT, 512, 1024, (size_t)512*1024, (size_t)1024*512);
  tr_k<<<dim3(16, 16, 4), 256, 0, stream>>>(ow, owT, 512, 512, (size_t)512*512, (size_t)512*512);

  // x = tokens @ in_proj_w + b   (128 M-tiles x 4 N-tiles = 512 blocks, 2/CU)
  gemm_k<<<512, 512, 0, stream>>>(tb16, inwT, in_b, nullptr, x, nullptr, nullptr,
                                  512, 768, 0);

  for (int i = 0; i < 4; ++i) {
    ln_k<<<4096, 256, 0, stream>>>(x, nw + i*512, nb + i*512, hy16);
    // (h @ iw + ib): 128 x 8 = 1024 blocks, 3/CU resident x 8 waves = 75% occ
    gemm_k<<<1024, 512, 0, stream>>>(hy16, iwT + (size_t)i*1024*512, ib + i*1024,
                                     nullptr, nullptr, g16, xin16, 1024, 512, 1);
    // 32 ch-groups x 16 batch = 512 blocks, 2/CU
    scan2d_k<<<dim3(32, 16), 512, 0, stream>>>(xin16, cw + i*9*512, cb + i*512,
                                               al + i*512, bbv + i*512, ccv + i*512,
                                               ddv + i*512, g16, hy16);
    // (yg @ ow + ob + x): 128 x 4 = 512 blocks
    gemm_k<<<512, 512, 0, stream>>>(hy16, owT + (size_t)i*512*512, obv + i*512,
                                    x, x, nullptr, nullptr, 512, 512, 2);
  }

  ln_k<<<4096, 256, 0, stream>>>(x, onw, onb, hy16);
  reduce_k<<<dim3(16, 8), 256, 0, stream>>>(hy16, (float*)d_out);
}